// Round 4
// baseline (381.618 us; speedup 1.0000x reference)
//
#include <hip/hip_runtime.h>
#include <math.h>

#define T_ 128
#define B_ 64
#define H_ 512
#define E_ 256
#define V_ 32000
#define VT_ (V_ + T_)   // 32128
#define UNK_ 2
#define EPS_ 1e-10f
#define NP_ (V_ / 64)   // 500 proj blocks -> per-row softmax partials

typedef __attribute__((ext_vector_type(8))) _Float16 half8;
typedef __attribute__((ext_vector_type(2))) _Float16 half2v;
typedef __attribute__((ext_vector_type(4))) float floatx4;

// ---------------- K1: fused prologue ----------------
// ranges: zero(score) | cvt+transpose enc->f16 (B,T,H) | cvt attn_W[:,512:]
//         | cvt copy1_W | Wh MFMA mini-GEMM | build Wcat f16 (gate-interleaved)
//         | xg emb | xg h | bcat
#define NB_ZERO 32      // 8192 floats (score)
#define NB_CVTE 2048    // 4,194,304 elems / 8 / 256
#define NB_CVTA 512
#define NB_CVTC 512
#define NB_WHM  8       // 64x512 GEMM as 8 MFMA blocks
#define NB_CVTW 2048    // one block per Wcat row
#define NB_XE   64      // 64*256 / 256
#define NB_XH   128     // 64*512 / 256
#define NB_BC   8       // 2048 / 256
#define NB_PRO (NB_ZERO + NB_CVTE + NB_CVTA + NB_CVTC + NB_WHM + NB_CVTW + NB_XE + NB_XH + NB_BC)

// Gate-interleaved Wcat layout: permuted row mp (0..2047):
//   blk = mp>>6, q = (mp>>4)&3, idx = mp&15, hh = blk*16+idx
//   q=0 -> r-gate row hh:      [Wih_r | Whh_r]
//   q=1 -> z-gate row 512+hh:  [Wih_z | Whh_z]
//   q=2 -> n_i row 1024+hh:    [Wih_n | 0]
//   q=3 -> n_h row 1024+hh:    [0 | Whh_n]
__global__ __launch_bounds__(256) void prologue_k(
        const float* __restrict__ u_enc, const float* __restrict__ attn_W,
        const float* __restrict__ copy1_W, const float* __restrict__ last_h,
        const float* __restrict__ attn_b, const float* __restrict__ emb,
        const int* __restrict__ z, const float* __restrict__ Wih,
        const float* __restrict__ Whh, const float* __restrict__ bih,
        const float* __restrict__ bhh,
        float* __restrict__ zbase, _Float16* __restrict__ enc_bh,
        _Float16* __restrict__ Wb_attn, _Float16* __restrict__ Wb_copy,
        float* __restrict__ Wh, _Float16* __restrict__ Wcat,
        _Float16* __restrict__ xg, float* __restrict__ bcat) {
    int bid = blockIdx.x, tid = threadIdx.x;
    if (bid < NB_ZERO) { zbase[bid * 256 + tid] = 0.f; return; }
    bid -= NB_ZERO;
    if (bid < NB_CVTE) {
        int idx8 = bid * 256 + tid;      // one half8 per thread
        int i = idx8 * 8;
        float4 a = *(const float4*)(u_enc + i);
        float4 b4 = *(const float4*)(u_enc + i + 4);
        half8 o;
        o[0] = (_Float16)a.x; o[1] = (_Float16)a.y; o[2] = (_Float16)a.z; o[3] = (_Float16)a.w;
        o[4] = (_Float16)b4.x; o[5] = (_Float16)b4.y; o[6] = (_Float16)b4.z; o[7] = (_Float16)b4.w;
        int h8 = idx8 & 63;              // H/8 = 64 chunks per row
        int tb = idx8 >> 6;              // t*B + b
        int b = tb & 63, t = tb >> 6;
        *(half8*)(enc_bh + ((size_t)(b * T_ + t) * H_) + h8 * 8) = o;   // (B,T,H)
        return;
    }
    bid -= NB_CVTE;
    if (bid < NB_CVTA) {
        int c = tid * 2;
        float2 v = *(const float2*)(attn_W + (size_t)bid * 1024 + 512 + c);
        Wb_attn[bid * 512 + c]     = (_Float16)v.x;
        Wb_attn[bid * 512 + c + 1] = (_Float16)v.y;
        return;
    }
    bid -= NB_CVTA;
    if (bid < NB_CVTC) {
        int c = tid * 2;
        float2 v = *(const float2*)(copy1_W + (size_t)bid * 512 + c);
        Wb_copy[bid * 512 + c]     = (_Float16)v.x;
        Wb_copy[bid * 512 + c + 1] = (_Float16)v.y;
        return;
    }
    bid -= NB_CVTC;
    if (bid < NB_WHM) {
        // Wh = last_h @ attn_W[:, :512]^T + attn_b   (64 x 512), MFMA
        int lane = tid & 63, wave = tid >> 6;
        int n0 = bid * 64 + wave * 16;
        int coln = lane & 15;
        int kq = (lane >> 4) * 8;
        const float* wrow = attn_W + (size_t)(n0 + coln) * 1024 + kq;
        const float* arow0 = last_h + kq;
        floatx4 acc[4] = {};
        #pragma unroll 4
        for (int k0 = 0; k0 < 512; k0 += 32) {
            const float4* wb = (const float4*)(wrow + k0);
            float4 w0 = wb[0], w1 = wb[1];
            half8 fb;
            fb[0] = (_Float16)w0.x; fb[1] = (_Float16)w0.y; fb[2] = (_Float16)w0.z; fb[3] = (_Float16)w0.w;
            fb[4] = (_Float16)w1.x; fb[5] = (_Float16)w1.y; fb[6] = (_Float16)w1.z; fb[7] = (_Float16)w1.w;
            #pragma unroll
            for (int mi = 0; mi < 4; ++mi) {
                const float4* ab = (const float4*)(arow0 + (size_t)(mi * 16 + coln) * 512 + k0);
                float4 a0 = ab[0], a1 = ab[1];
                half8 fa;
                fa[0] = (_Float16)a0.x; fa[1] = (_Float16)a0.y; fa[2] = (_Float16)a0.z; fa[3] = (_Float16)a0.w;
                fa[4] = (_Float16)a1.x; fa[5] = (_Float16)a1.y; fa[6] = (_Float16)a1.z; fa[7] = (_Float16)a1.w;
                acc[mi] = __builtin_amdgcn_mfma_f32_16x16x32_f16(fa, fb, acc[mi], 0, 0, 0);
            }
        }
        int rbase = (lane >> 4) * 4;
        float bias = attn_b[n0 + coln];
        #pragma unroll
        for (int mi = 0; mi < 4; ++mi)
            #pragma unroll
            for (int r = 0; r < 4; ++r)
                Wh[(size_t)(mi * 16 + rbase + r) * 512 + n0 + coln] = acc[mi][r] + bias;
        return;
    }
    bid -= NB_WHM;
    if (bid < NB_CVTW) {
        int mp = bid;
        int q  = (mp >> 4) & 3;
        int hh = (mp >> 6) * 16 + (mp & 15);
        #pragma unroll
        for (int j = 0; j < 5; ++j) {
            int c = j * 256 + tid;
            float w;
            if (q == 0)      w = (c < 768) ? Wih[(size_t)hh * 768 + c]
                                           : Whh[(size_t)hh * 512 + (c - 768)];
            else if (q == 1) w = (c < 768) ? Wih[(size_t)(512 + hh) * 768 + c]
                                           : Whh[(size_t)(512 + hh) * 512 + (c - 768)];
            else if (q == 2) w = (c < 768) ? Wih[(size_t)(1024 + hh) * 768 + c] : 0.f;
            else             w = (c >= 768) ? Whh[(size_t)(1024 + hh) * 512 + (c - 768)] : 0.f;
            Wcat[(size_t)mp * 1280 + c] = (_Float16)w;
        }
        return;
    }
    bid -= NB_CVTW;
    if (bid < NB_XE) {
        int idx = bid * 256 + tid;
        int bb = idx >> 8, c = idx & 255;
        xg[bb * 1280 + c] = (_Float16)emb[(size_t)z[bb] * E_ + c];
        return;
    }
    bid -= NB_XE;
    if (bid < NB_XH) {
        int idx = bid * 256 + tid;
        int bb = idx >> 9, c = idx & 511;
        xg[bb * 1280 + 768 + c] = (_Float16)last_h[bb * H_ + c];
        return;
    }
    bid -= NB_XH;
    {
        int mp = bid * 256 + tid;
        int q  = (mp >> 4) & 3;
        int hh = (mp >> 6) * 16 + (mp & 15);
        float v2;
        if (q == 0)      v2 = bih[hh] + bhh[hh];
        else if (q == 1) v2 = bih[512 + hh] + bhh[512 + hh];
        else if (q == 2) v2 = bih[1024 + hh];
        else             v2 = bhh[1024 + hh];
        bcat[mp] = v2;
    }
}

// ------- enc dual GEMM (f16 MFMA, LDS-staged A, XCD-remapped) -------
// A = enc_bh (B*T, H) row-major. Block: 64 rows x 64 cols x {Wa, Wc}.
__global__ __launch_bounds__(256) void enc_dual_k(
        const _Float16* __restrict__ enc_bh, // (B*T, H)
        const _Float16* __restrict__ Wa,     // (512,512)
        const _Float16* __restrict__ Wc,     // (512,512)
        const float* __restrict__ Wh,        // (B,H) add for attn
        const float* __restrict__ attn_v,    // (H)
        const float* __restrict__ copy1_b,   // (H)
        float* __restrict__ score,           // (B*T), zeroed
        _Float16* __restrict__ cs) {         // (B*T, H)
    __shared__ _Float16 As[64 * 512];        // 64 KB, swizzled
    int bid = blockIdx.x;
    // XCD remap: xcd = bid&7 owns 16 contiguous row-tiles across all 8 col-tiles
    int xcd = bid & 7, loc = bid >> 3;
    int xt = xcd * 16 + (loc & 15);          // row-tile 0..127
    int yt = loc >> 4;                       // col-tile 0..7
    int r0 = xt * 64;
    int b  = r0 >> 7;                        // r0 / T_
    int tid = threadIdx.x;
    int lane = tid & 63, wave = tid >> 6;
    // ---- stage A tile: coalesced global read, swizzled LDS write ----
    const half8* src = (const half8*)(enc_bh + (size_t)r0 * H_);
    #pragma unroll
    for (int i = 0; i < 16; ++i) {
        int G = i * 256 + tid;               // 16B-seg index, 0..4095
        half8 v = src[G];
        int r = G >> 6, s = G & 63;
        *(half8*)&As[(size_t)(((r << 6) | (s ^ (r & 7))) << 3)] = v;
    }
    __syncthreads();
    int n0 = yt * 64 + wave * 16;
    int coln = lane & 15;
    int g = lane >> 4;
    const _Float16* wra = Wa + (size_t)(n0 + coln) * H_ + g * 8;
    const _Float16* wrc = Wc + (size_t)(n0 + coln) * H_ + g * 8;
    floatx4 acca[4] = {}, accc[4] = {};
    #pragma unroll 4
    for (int k0 = 0; k0 < H_; k0 += 32) {
        half8 fba = *(const half8*)(wra + k0);
        half8 fbc = *(const half8*)(wrc + k0);
        #pragma unroll
        for (int mi = 0; mi < 4; ++mi) {
            int r = mi * 16 + coln;
            half8 fa = *(const half8*)&As[((size_t)r << 9) +
                          ((((k0 >> 3) + g) ^ (coln & 7)) << 3)];
            acca[mi] = __builtin_amdgcn_mfma_f32_16x16x32_f16(fa, fba, acca[mi], 0, 0, 0);
            accc[mi] = __builtin_amdgcn_mfma_f32_16x16x32_f16(fa, fbc, accc[mi], 0, 0, 0);
        }
    }
    int col = n0 + coln;
    float addt = Wh[b * H_ + col];
    float av   = attn_v[col];
    float cb   = copy1_b[col];
    int rbase = g * 4;
    #pragma unroll
    for (int mi = 0; mi < 4; ++mi)
        #pragma unroll
        for (int r = 0; r < 4; ++r) {
            int row = r0 + mi * 16 + rbase + r;
            float x = acca[mi][r] + addt;
            float t2 = __expf(2.f * x);
            float v = av * ((t2 - 1.f) / (t2 + 1.f));
            v += __shfl_xor(v, 1);
            v += __shfl_xor(v, 2);
            v += __shfl_xor(v, 4);
            v += __shfl_xor(v, 8);
            if (coln == 0) atomicAdd(&score[row], v);
            float y = accc[mi][r] + cb;
            float t3 = __expf(2.f * y);
            cs[(size_t)row * H_ + col] = (_Float16)((t3 - 1.f) / (t3 + 1.f));
        }
}

// ------- softmax over T + ctx, vectorized: one block per b, 2 cols/thread ----
__global__ __launch_bounds__(256) void softctx_k(
        const float* __restrict__ score, const _Float16* __restrict__ enc_bh,
        _Float16* __restrict__ xcat, _Float16* __restrict__ xg) {
    __shared__ float al[T_];
    __shared__ float red[T_];
    int b = blockIdx.x, tid = threadIdx.x;
    float v = (tid < T_) ? score[b * T_ + tid] : -1e30f;
    if (tid < T_) red[tid] = v;
    __syncthreads();
    for (int s = 64; s > 0; s >>= 1) { if (tid < s) red[tid] = fmaxf(red[tid], red[tid + s]); __syncthreads(); }
    float m = red[0]; __syncthreads();
    float e = (tid < T_) ? __expf(v - m) : 0.f;
    if (tid < T_) red[tid] = e;
    __syncthreads();
    for (int s = 64; s > 0; s >>= 1) { if (tid < s) red[tid] += red[tid + s]; __syncthreads(); }
    if (tid < T_) al[tid] = e / red[0];
    __syncthreads();
    // ctx: thread owns 2 adjacent h columns; each t-iter is one coalesced 1KB row
    const half2v* ebase = (const half2v*)(enc_bh + (size_t)b * T_ * H_) + tid;
    float s0 = 0.f, s1 = 0.f;
    #pragma unroll 8
    for (int t = 0; t < T_; ++t) {
        half2v u = ebase[(size_t)t * 256];
        float a = al[t];
        s0 += a * (float)u[0];
        s1 += a * (float)u[1];
    }
    int h0 = tid * 2;
    half2v o; o[0] = (_Float16)s0; o[1] = (_Float16)s1;
    *(half2v*)(xcat + b * 1024 + 512 + h0) = o;
    *(half2v*)(xg + b * 1280 + 256 + h0)   = o;
}

// ------- GRU gates GEMM + fused elementwise; 512 thr, K-split across waves ---
__global__ __launch_bounds__(512) void grucat_k(
        const _Float16* __restrict__ xg,    // (64,1280)
        const _Float16* __restrict__ Wcat,  // (2048,1280) permuted rows
        const float* __restrict__ bcat,     // (2048) permuted
        const float* __restrict__ hprev,    // (64,512)
        float* __restrict__ out,            // gru_out + new_hidden
        _Float16* __restrict__ xcat) {      // (64,1024), writes [:,0:512]
    __shared__ float Lt[8][64][17];         // [wave][batch][hidden-idx], padded
    int tid = threadIdx.x;
    int lane = tid & 63, wave = tid >> 6;
    int q = wave & 3, khalf = wave >> 2;
    int n0 = blockIdx.x * 64 + q * 16;
    int coln = lane & 15;
    int kq  = (lane >> 4) * 8;
    int kbase = khalf * 640;
    const _Float16* wrow  = Wcat + (size_t)(n0 + coln) * 1280 + kbase + kq;
    const _Float16* abase = xg + kbase + kq;
    floatx4 acc[4] = {};
    #pragma unroll 5
    for (int k0 = 0; k0 < 640; k0 += 32) {
        half8 fb = *(const half8*)(wrow + k0);
        #pragma unroll
        for (int mi = 0; mi < 4; ++mi) {
            half8 fa = *(const half8*)(abase + (size_t)(mi * 16 + coln) * 1280 + k0);
            acc[mi] = __builtin_amdgcn_mfma_f32_16x16x32_f16(fa, fb, acc[mi], 0, 0, 0);
        }
    }
    int rbase = (lane >> 4) * 4;
    #pragma unroll
    for (int mi = 0; mi < 4; ++mi)
        #pragma unroll
        for (int r = 0; r < 4; ++r)
            Lt[wave][mi * 16 + rbase + r][coln] = acc[mi][r];
    __syncthreads();
    int HB = blockIdx.x * 16;
    #pragma unroll
    for (int p = tid; p < 1024; p += 512) {
        int b = p >> 4, i = p & 15;
        float G0 = Lt[0][b][i] + Lt[4][b][i] + bcat[blockIdx.x * 64 + i];
        float G1 = Lt[1][b][i] + Lt[5][b][i] + bcat[blockIdx.x * 64 + 16 + i];
        float G2 = Lt[2][b][i] + Lt[6][b][i] + bcat[blockIdx.x * 64 + 32 + i];
        float G3 = Lt[3][b][i] + Lt[7][b][i] + bcat[blockIdx.x * 64 + 48 + i];
        float rr = 1.f / (1.f + __expf(-G0));
        float zz = 1.f / (1.f + __expf(-G1));
        float nn = tanhf(G2 + rr * G3);
        float h  = hprev[b * H_ + HB + i];
        float hv = (1.f - zz) * nn + zz * h;
        out[b * H_ + HB + i] = hv;               // gru_out
        out[B_ * H_ + b * H_ + HB + i] = hv;     // new_hidden
        xcat[b * 1024 + HB + i] = (_Float16)hv;
    }
}

// ------- gen_score via f16 MFMA + fused per-block softmax partials -------
__global__ __launch_bounds__(256) void proj_stats_k(
        const _Float16* __restrict__ xcat,  // (64,1024)
        const float* __restrict__ Wp,       // (V,1024) fp32
        const float* __restrict__ bp,       // (V)
        float* __restrict__ gen,            // (64,V)
        float* __restrict__ mpart, float* __restrict__ lpart) {  // (B,NP)
    __shared__ float m_lds[4][64];
    __shared__ float l_lds[4][64];
    int lane = threadIdx.x & 63;
    int wave = threadIdx.x >> 6;
    int n0 = (blockIdx.x * 4 + wave) * 16;
    int coln = lane & 15;
    int kq  = (lane >> 4) * 8;
    const float* wrow = Wp + (size_t)(n0 + coln) * 1024 + kq;
    const _Float16* abase = xcat + kq;
    floatx4 acc[4] = {};
    #pragma unroll 8
    for (int k0 = 0; k0 < 1024; k0 += 32) {
        const float4* wb = (const float4*)(wrow + k0);
        float4 w0 = wb[0], w1 = wb[1];
        half8 fb;
        fb[0] = (_Float16)w0.x; fb[1] = (_Float16)w0.y; fb[2] = (_Float16)w0.z; fb[3] = (_Float16)w0.w;
        fb[4] = (_Float16)w1.x; fb[5] = (_Float16)w1.y; fb[6] = (_Float16)w1.z; fb[7] = (_Float16)w1.w;
        #pragma unroll
        for (int mi = 0; mi < 4; ++mi) {
            half8 fa = *(const half8*)(abase + (size_t)(mi * 16 + coln) * 1024 + k0);
            acc[mi] = __builtin_amdgcn_mfma_f32_16x16x32_f16(fa, fb, acc[mi], 0, 0, 0);
        }
    }
    int rbase = (lane >> 4) * 4;
    float bias = bp[n0 + coln];
    #pragma unroll
    for (int mi = 0; mi < 4; ++mi)
        #pragma unroll
        for (int r = 0; r < 4; ++r) {
            int brow = mi * 16 + rbase + r;
            float x = acc[mi][r] + bias;
            gen[(size_t)brow * V_ + n0 + coln] = x;
            float mm = x;
            mm = fmaxf(mm, __shfl_xor(mm, 1));
            mm = fmaxf(mm, __shfl_xor(mm, 2));
            mm = fmaxf(mm, __shfl_xor(mm, 4));
            mm = fmaxf(mm, __shfl_xor(mm, 8));
            float e = __expf(x - mm);
            e += __shfl_xor(e, 1);
            e += __shfl_xor(e, 2);
            e += __shfl_xor(e, 4);
            e += __shfl_xor(e, 8);
            if (coln == 0) { m_lds[wave][brow] = mm; l_lds[wave][brow] = e; }
        }
    __syncthreads();
    if (threadIdx.x < 64) {
        int bb = threadIdx.x;
        float M = m_lds[0][bb], L = l_lds[0][bb];
        #pragma unroll
        for (int w = 1; w < 4; ++w) {
            float m2 = m_lds[w][bb], l2 = l_lds[w][bb];
            float nm = fmaxf(M, m2);
            L = L * __expf(M - nm) + l2 * __expf(m2 - nm);
            M = nm;
        }
        mpart[bb * NP_ + blockIdx.x] = M;
        lpart[bb * NP_ + blockIdx.x] = L;
    }
}

// ---- raw = cs . h_new + copy stats + scatter + FUSED params combine ----
__global__ __launch_bounds__(256) void raw_epi_k(
        const _Float16* __restrict__ cs, const float* __restrict__ hnew,
        const int* __restrict__ u_input,
        const float* __restrict__ mpart, const float* __restrict__ lpart,
        float* __restrict__ scat, float* __restrict__ params) {
    __shared__ float rawS[T_];
    __shared__ float red[T_];
    __shared__ float ms[256], ls[256];
    int b = blockIdx.x, tid = threadIdx.x;
    int lane = tid & 63, wave = tid >> 6;
    const float4* hp = (const float4*)(hnew + b * H_ + lane * 8);
    float4 ha = hp[0], hb = hp[1];
    #pragma unroll 4
    for (int i = 0; i < 32; ++i) {
        int t = wave * 32 + i;
        half8 c8 = *(const half8*)(cs + (size_t)(b * T_ + t) * H_ + lane * 8);
        float s = (float)c8[0] * ha.x + (float)c8[1] * ha.y + (float)c8[2] * ha.z + (float)c8[3] * ha.w
                + (float)c8[4] * hb.x + (float)c8[5] * hb.y + (float)c8[6] * hb.z + (float)c8[7] * hb.w;
        #pragma unroll
        for (int off = 32; off > 0; off >>= 1) s += __shfl_down(s, off);
        if (lane == 0) rawS[t] = s;
    }
    __syncthreads();
    int t = tid;
    float v = (t < T_) ? rawS[t] : -1e30f;
    if (t < T_) red[t] = v;
    __syncthreads();
    for (int s = 64; s > 0; s >>= 1) { if (t < s) red[t] = fmaxf(red[t], red[t + s]); __syncthreads(); }
    float cm = red[0]; __syncthreads();
    float e = (t < T_) ? __expf(v - cm) : 0.f;
    if (t < T_) red[t] = e;
    __syncthreads();
    for (int s = 64; s > 0; s >>= 1) { if (t < s) red[t] += red[t + s]; __syncthreads(); }
    float tot = red[0]; __syncthreads();
    int id = (t < T_) ? u_input[t * B_ + b] : 0;
    size_t j = (size_t)b * VT_ + ((id == UNK_) ? (V_ + t) : id);
    if (id != 0) scat[j] = 0.f;
    __syncthreads();
    if (id != 0) atomicAdd(&scat[j], e);
    if (t < T_) red[t] = (id != 0) ? e : 0.f;
    __syncthreads();
    for (int s = 64; s > 0; s >>= 1) { if (t < s) red[t] += red[t + s]; __syncthreads(); }
    float ssum = red[0]; __syncthreads();
    float sv = (id != 0) ? scat[j] : 0.f;
    if (t < T_) red[t] = sv;
    __syncthreads();
    for (int s = 64; s > 0; s >>= 1) { if (t < s) red[t] = fmaxf(red[t], red[t + s]); __syncthreads(); }
    float smax = red[0]; __syncthreads();
    // fused combine of gen-softmax partials (all 256 threads)
    float M = -1e30f, L = 0.f;
    for (int s = t; s < NP_; s += 256) {
        float m2 = mpart[b * NP_ + s], l2 = lpart[b * NP_ + s];
        float nm = fmaxf(M, m2);
        L = L * __expf(M - nm) + l2 * __expf(m2 - nm);
        M = nm;
    }
    ms[t] = M; ls[t] = L;
    __syncthreads();
    for (int s = 128; s > 0; s >>= 1) {
        if (t < s) {
            float m2 = ms[t + s], l2 = ls[t + s];
            float nm = fmaxf(ms[t], m2);
            ls[t] = ls[t] * __expf(ms[t] - nm) + l2 * __expf(m2 - nm);
            ms[t] = nm;
        }
        __syncthreads();
    }
    if (t == 0) {
        float Mg = ms[0], Zg = ls[0];
        float umax = cm + logf(EPS_ * tot + (1.f - EPS_) * smax);
        float M2 = fmaxf(Mg, umax);
        float coef = __expf(cm - M2);
        float Z = Zg * __expf(Mg - M2) + coef * (EPS_ * tot * (float)VT_ + (1.f - EPS_) * ssum);
        float invZ = 1.f / Z;
        params[b * 4 + 0] = M2;
        params[b * 4 + 1] = invZ;
        params[b * 4 + 2] = coef * EPS_ * tot * invZ;      // addc
        params[b * 4 + 3] = coef * (1.f - EPS_) * invZ;    // scoef
    }
}

// ---------------- streamed proba write (no scat read) ----------------
__global__ __launch_bounds__(256) void write_k(const float* __restrict__ gen,
                                               const float* __restrict__ params,
                                               float* __restrict__ proba) {
    int b = blockIdx.y;
    int i4 = blockIdx.x * 256 + threadIdx.x;   // float4 index
    if (i4 >= VT_ / 4) return;
    float M = params[b * 4], invZ = params[b * 4 + 1], addc = params[b * 4 + 2];
    int j = i4 * 4;
    float4 p;
    if (j < V_) {
        float4 g = *(const float4*)(gen + (size_t)b * V_ + j);
        p.x = addc + __expf(g.x - M) * invZ;
        p.y = addc + __expf(g.y - M) * invZ;
        p.z = addc + __expf(g.z - M) * invZ;
        p.w = addc + __expf(g.w - M) * invZ;
    } else {
        p.x = p.y = p.z = p.w = addc;
    }
    *(float4*)(proba + (size_t)b * VT_ + j) = p;
}

// ---------------- overwrite scattered positions with full value ----------
__global__ void fix_k(const float* __restrict__ gen, const float* __restrict__ scat,
                      const int* __restrict__ u_input, const float* __restrict__ params,
                      float* __restrict__ proba) {
    int b = blockIdx.x, t = threadIdx.x;
    int id = u_input[t * B_ + b];
    if (id == 0) return;
    int j = (id == UNK_) ? (V_ + t) : id;
    float M = params[b * 4], invZ = params[b * 4 + 1];
    float addc = params[b * 4 + 2], scoef = params[b * 4 + 3];
    float p = addc + scoef * scat[(size_t)b * VT_ + j];
    if (j < V_) p += __expf(gen[(size_t)b * V_ + j] - M) * invZ;
    proba[(size_t)b * VT_ + j] = p;
}

extern "C" void kernel_launch(void* const* d_in, const int* in_sizes, int n_in,
                              void* d_out, int out_size, void* d_ws, size_t ws_size,
                              hipStream_t stream) {
    const float* u_enc   = (const float*)d_in[0];
    const int*   z_tm1   = (const int*)d_in[1];
    const float* last_h  = (const float*)d_in[2];
    const int*   u_input = (const int*)d_in[3];
    const float* emb     = (const float*)d_in[4];
    const float* attn_W  = (const float*)d_in[5];
    const float* attn_b  = (const float*)d_in[6];
    const float* attn_v  = (const float*)d_in[7];
    const float* gru_Wih = (const float*)d_in[8];
    const float* gru_Whh = (const float*)d_in[9];
    const float* gru_bih = (const float*)d_in[10];
    const float* gru_bhh = (const float*)d_in[11];
    const float* proj_W  = (const float*)d_in[12];
    const float* proj_b  = (const float*)d_in[13];
    const float* copy1_W = (const float*)d_in[14];
    const float* copy1_b = (const float*)d_in[15];
    float* out = (float*)d_out;

    float* ws    = (float*)d_ws;
    float* score = ws;                          // B*T (zeroed by prologue)
    float* gen   = score + B_ * T_;             // B*V (direct store)
    float* scat  = gen + (size_t)B_ * V_;       // B*VT (sparse-zeroed)
    float* Wh    = scat + (size_t)B_ * VT_;     // B*H
    float* mpart = Wh + B_ * H_;                // B*NP
    float* lpart = mpart + B_ * NP_;            // B*NP
    float* params= lpart + B_ * NP_;            // B*4
    float* bcat  = params + B_ * 4;             // 2048
    _Float16* xcat  = (_Float16*)(bcat + 2048);        // 64*1024
    _Float16* xg    = xcat + B_ * 1024;                // 64*1280
    _Float16* enc_bh = xg + B_ * 1280;                 // (B,T,H) f16
    _Float16* Wb_attn = enc_bh + (size_t)T_ * B_ * H_; // 512*512
    _Float16* Wb_copy = Wb_attn + H_ * H_;             // 512*512
    _Float16* Wcat  = Wb_copy + H_ * H_;               // 2048*1280
    _Float16* cs    = Wcat + 2048 * 1280;              // 8192*512

    prologue_k<<<NB_PRO, 256, 0, stream>>>(u_enc, attn_W, copy1_W, last_h, attn_b,
                                           emb, z_tm1, gru_Wih, gru_Whh, gru_bih, gru_bhh,
                                           score, enc_bh, Wb_attn, Wb_copy, Wh, Wcat, xg, bcat);

    enc_dual_k<<<1024, 256, 0, stream>>>(enc_bh, Wb_attn, Wb_copy, Wh, attn_v, copy1_b,
                                         score, cs);

    softctx_k<<<B_, 256, 0, stream>>>(score, enc_bh, xcat, xg);

    grucat_k<<<32, 512, 0, stream>>>(xg, Wcat, bcat, last_h, out, xcat);

    proj_stats_k<<<NP_, 256, 0, stream>>>(xcat, proj_W, proj_b, gen, mpart, lpart);

    raw_epi_k<<<B_, 256, 0, stream>>>(cs, out, u_input, mpart, lpart, scat, params);

    float* proba = out + 2 * B_ * H_;
    write_k<<<dim3((VT_ / 4 + 255) / 256, B_), 256, 0, stream>>>(gen, params, proba);
    fix_k<<<B_, T_, 0, stream>>>(gen, scat, u_input, params, proba);
}

// Round 5
// 372.824 us; speedup vs baseline: 1.0236x; 1.0236x over previous
//
#include <hip/hip_runtime.h>
#include <math.h>

#define T_ 128
#define B_ 64
#define H_ 512
#define E_ 256
#define V_ 32000
#define VT_ (V_ + T_)   // 32128
#define UNK_ 2
#define EPS_ 1e-10f
#define NP_ (V_ / 64)   // 500 proj blocks -> per-row softmax partials

typedef __attribute__((ext_vector_type(8))) _Float16 half8;
typedef __attribute__((ext_vector_type(2))) _Float16 half2v;
typedef __attribute__((ext_vector_type(4))) float floatx4;

// ---------------- K1: fused prologue ----------------
// ranges: zero(score) | cvt attn_W[:,512:] | cvt copy1_W | Wh matvec
//         | build Wcat f16 (gate-interleaved) | xg emb | xg h | bcat
#define NB_ZERO 32      // 8192 floats (score)
#define NB_CVTA 512
#define NB_CVTC 512
#define NB_WH   8192    // 64*512 waves / 4
#define NB_CVTW 2048    // one block per Wcat row
#define NB_XE   64      // 64*256 / 256
#define NB_XH   128     // 64*512 / 256
#define NB_BC   8       // 2048 / 256
#define NB_PRO (NB_ZERO + NB_CVTA + NB_CVTC + NB_WH + NB_CVTW + NB_XE + NB_XH + NB_BC)

// Gate-interleaved Wcat layout: permuted row mp (0..2047):
//   blk = mp>>6, q = (mp>>4)&3, idx = mp&15, hh = blk*16+idx
//   q=0 -> r-gate row hh:      [Wih_r | Whh_r]
//   q=1 -> z-gate row 512+hh:  [Wih_z | Whh_z]
//   q=2 -> n_i row 1024+hh:    [Wih_n | 0]
//   q=3 -> n_h row 1024+hh:    [0 | Whh_n]
__global__ __launch_bounds__(256) void prologue_k(
        const float* __restrict__ attn_W,
        const float* __restrict__ copy1_W, const float* __restrict__ last_h,
        const float* __restrict__ attn_b, const float* __restrict__ emb,
        const int* __restrict__ z, const float* __restrict__ Wih,
        const float* __restrict__ Whh, const float* __restrict__ bih,
        const float* __restrict__ bhh,
        float* __restrict__ zbase,
        _Float16* __restrict__ Wb_attn, _Float16* __restrict__ Wb_copy,
        float* __restrict__ Wh, _Float16* __restrict__ Wcat,
        _Float16* __restrict__ xg, float* __restrict__ bcat) {
    int bid = blockIdx.x, tid = threadIdx.x;
    if (bid < NB_ZERO) { zbase[bid * 256 + tid] = 0.f; return; }
    bid -= NB_ZERO;
    if (bid < NB_CVTA) {
        int c = tid * 2;
        float2 v = *(const float2*)(attn_W + (size_t)bid * 1024 + 512 + c);
        Wb_attn[bid * 512 + c]     = (_Float16)v.x;
        Wb_attn[bid * 512 + c + 1] = (_Float16)v.y;
        return;
    }
    bid -= NB_CVTA;
    if (bid < NB_CVTC) {
        int c = tid * 2;
        float2 v = *(const float2*)(copy1_W + (size_t)bid * 512 + c);
        Wb_copy[bid * 512 + c]     = (_Float16)v.x;
        Wb_copy[bid * 512 + c + 1] = (_Float16)v.y;
        return;
    }
    bid -= NB_CVTC;
    if (bid < NB_WH) {
        int wid = bid * 4 + (tid >> 6), lane = tid & 63;
        int b = wid >> 9, m = wid & 511;
        const float4* wr = (const float4*)(attn_W + (size_t)m * 1024);
        const float4* xr = (const float4*)(last_h + b * 512);
        float s = 0.f;
        #pragma unroll
        for (int i = 0; i < 2; ++i) {
            int k = lane + i * 64;
            float4 w = wr[k], x = xr[k];
            s += w.x * x.x + w.y * x.y + w.z * x.z + w.w * x.w;
        }
        #pragma unroll
        for (int off = 32; off > 0; off >>= 1) s += __shfl_down(s, off);
        if (lane == 0) Wh[b * 512 + m] = s + attn_b[m];
        return;
    }
    bid -= NB_WH;
    if (bid < NB_CVTW) {
        int mp = bid;
        int q  = (mp >> 4) & 3;
        int hh = (mp >> 6) * 16 + (mp & 15);
        #pragma unroll
        for (int j = 0; j < 5; ++j) {
            int c = j * 256 + tid;
            float w;
            if (q == 0)      w = (c < 768) ? Wih[(size_t)hh * 768 + c]
                                           : Whh[(size_t)hh * 512 + (c - 768)];
            else if (q == 1) w = (c < 768) ? Wih[(size_t)(512 + hh) * 768 + c]
                                           : Whh[(size_t)(512 + hh) * 512 + (c - 768)];
            else if (q == 2) w = (c < 768) ? Wih[(size_t)(1024 + hh) * 768 + c] : 0.f;
            else             w = (c >= 768) ? Whh[(size_t)(1024 + hh) * 512 + (c - 768)] : 0.f;
            Wcat[(size_t)mp * 1280 + c] = (_Float16)w;
        }
        return;
    }
    bid -= NB_CVTW;
    if (bid < NB_XE) {
        int idx = bid * 256 + tid;
        int bb = idx >> 8, c = idx & 255;
        xg[bb * 1280 + c] = (_Float16)emb[(size_t)z[bb] * E_ + c];
        return;
    }
    bid -= NB_XE;
    if (bid < NB_XH) {
        int idx = bid * 256 + tid;
        int bb = idx >> 9, c = idx & 511;
        xg[bb * 1280 + 768 + c] = (_Float16)last_h[bb * H_ + c];
        return;
    }
    bid -= NB_XH;
    {
        int mp = bid * 256 + tid;
        int q  = (mp >> 4) & 3;
        int hh = (mp >> 6) * 16 + (mp & 15);
        float v2;
        if (q == 0)      v2 = bih[hh] + bhh[hh];
        else if (q == 1) v2 = bih[512 + hh] + bhh[512 + hh];
        else if (q == 2) v2 = bih[1024 + hh];
        else             v2 = bhh[1024 + hh];
        bcat[mp] = v2;
    }
}

// ------- enc dual GEMM (f16 MFMA, LDS-staged A w/ in-flight fp32->f16 cvt,
//         XCD-remapped). A logical row (b,t) read from u_enc (T,B,H) fp32. ----
__global__ __launch_bounds__(256) void enc_dual_k(
        const float* __restrict__ u_enc,     // (T,B,H) fp32
        const _Float16* __restrict__ Wa,     // (512,512)
        const _Float16* __restrict__ Wc,     // (512,512)
        const float* __restrict__ Wh,        // (B,H) add for attn
        const float* __restrict__ attn_v,    // (H)
        const float* __restrict__ copy1_b,   // (H)
        float* __restrict__ score,           // (B*T), zeroed
        _Float16* __restrict__ cs) {         // (B*T, H)
    __shared__ _Float16 As[64 * 512];        // 64 KB, swizzled
    int bid = blockIdx.x;
    // XCD remap: xcd = bid&7 owns 16 contiguous row-tiles across all 8 col-tiles
    int xcd = bid & 7, loc = bid >> 3;
    int xt = xcd * 16 + (loc & 15);          // row-tile 0..127
    int yt = loc >> 4;                       // col-tile 0..7
    int b  = xt >> 1;                        // tile never crosses b (T=128)
    int t0 = (xt & 1) * 64;
    int r0 = b * T_ + t0;                    // global row base (b*T + t)
    int tid = threadIdx.x;
    int lane = tid & 63, wave = tid >> 6;
    // ---- stage A tile: coalesced fp32 read + cvt, swizzled LDS write ----
    const float* srcb = u_enc + (size_t)t0 * B_ * H_ + (size_t)b * H_;
    #pragma unroll
    for (int i = 0; i < 16; ++i) {
        int G = i * 256 + tid;               // 8-elem-chunk index, 0..4095
        int r = G >> 6, s = G & 63;
        const float4* p = (const float4*)(srcb + (size_t)r * B_ * H_ + s * 8);
        float4 a0 = p[0], a1 = p[1];
        half8 v;
        v[0] = (_Float16)a0.x; v[1] = (_Float16)a0.y; v[2] = (_Float16)a0.z; v[3] = (_Float16)a0.w;
        v[4] = (_Float16)a1.x; v[5] = (_Float16)a1.y; v[6] = (_Float16)a1.z; v[7] = (_Float16)a1.w;
        *(half8*)&As[(size_t)(((r << 6) | (s ^ (r & 7))) << 3)] = v;
    }
    __syncthreads();
    int n0 = yt * 64 + wave * 16;
    int coln = lane & 15;
    int g = lane >> 4;
    const _Float16* wra = Wa + (size_t)(n0 + coln) * H_ + g * 8;
    const _Float16* wrc = Wc + (size_t)(n0 + coln) * H_ + g * 8;
    floatx4 acca[4] = {}, accc[4] = {};
    #pragma unroll 4
    for (int k0 = 0; k0 < H_; k0 += 32) {
        half8 fba = *(const half8*)(wra + k0);
        half8 fbc = *(const half8*)(wrc + k0);
        #pragma unroll
        for (int mi = 0; mi < 4; ++mi) {
            int r = mi * 16 + coln;
            half8 fa = *(const half8*)&As[((size_t)r << 9) +
                          ((((k0 >> 3) + g) ^ (coln & 7)) << 3)];
            acca[mi] = __builtin_amdgcn_mfma_f32_16x16x32_f16(fa, fba, acca[mi], 0, 0, 0);
            accc[mi] = __builtin_amdgcn_mfma_f32_16x16x32_f16(fa, fbc, accc[mi], 0, 0, 0);
        }
    }
    int col = n0 + coln;
    float addt = Wh[b * H_ + col];
    float av   = attn_v[col];
    float cb   = copy1_b[col];
    int rbase = g * 4;
    #pragma unroll
    for (int mi = 0; mi < 4; ++mi)
        #pragma unroll
        for (int r = 0; r < 4; ++r) {
            int row = r0 + mi * 16 + rbase + r;
            float x = acca[mi][r] + addt;
            float t2 = __expf(2.f * x);
            float v = av * ((t2 - 1.f) / (t2 + 1.f));
            v += __shfl_xor(v, 1);
            v += __shfl_xor(v, 2);
            v += __shfl_xor(v, 4);
            v += __shfl_xor(v, 8);
            if (coln == 0) atomicAdd(&score[row], v);
            float y = accc[mi][r] + cb;
            float t3 = __expf(2.f * y);
            cs[(size_t)row * H_ + col] = (_Float16)((t3 - 1.f) / (t3 + 1.f));
        }
}

// ------- softmax over T + ctx (reads u_enc fp32), 2 cols/thread ----
__global__ __launch_bounds__(256) void softctx_k(
        const float* __restrict__ score, const float* __restrict__ u_enc,
        _Float16* __restrict__ xcat, _Float16* __restrict__ xg) {
    __shared__ float al[T_];
    __shared__ float red[T_];
    int b = blockIdx.x, tid = threadIdx.x;
    float v = (tid < T_) ? score[b * T_ + tid] : -1e30f;
    if (tid < T_) red[tid] = v;
    __syncthreads();
    for (int s = 64; s > 0; s >>= 1) { if (tid < s) red[tid] = fmaxf(red[tid], red[tid + s]); __syncthreads(); }
    float m = red[0]; __syncthreads();
    float e = (tid < T_) ? __expf(v - m) : 0.f;
    if (tid < T_) red[tid] = e;
    __syncthreads();
    for (int s = 64; s > 0; s >>= 1) { if (tid < s) red[tid] += red[tid + s]; __syncthreads(); }
    if (tid < T_) al[tid] = e / red[0];
    __syncthreads();
    // ctx: thread owns 2 adjacent h columns; each t-iter is one coalesced 2KB row
    const float2* ebase = (const float2*)(u_enc + (size_t)b * H_) + tid;
    float s0 = 0.f, s1 = 0.f;
    #pragma unroll 8
    for (int t = 0; t < T_; ++t) {
        float2 u = ebase[(size_t)t * (B_ * H_ / 2)];
        float a = al[t];
        s0 += a * u.x;
        s1 += a * u.y;
    }
    int h0 = tid * 2;
    half2v o; o[0] = (_Float16)s0; o[1] = (_Float16)s1;
    *(half2v*)(xcat + b * 1024 + 512 + h0) = o;
    *(half2v*)(xg + b * 1280 + 256 + h0)   = o;
}

// ------- GRU gates GEMM + fused elementwise; 512 thr, K-split across waves ---
__global__ __launch_bounds__(512) void grucat_k(
        const _Float16* __restrict__ xg,    // (64,1280)
        const _Float16* __restrict__ Wcat,  // (2048,1280) permuted rows
        const float* __restrict__ bcat,     // (2048) permuted
        const float* __restrict__ hprev,    // (64,512)
        float* __restrict__ out,            // gru_out + new_hidden
        _Float16* __restrict__ xcat) {      // (64,1024), writes [:,0:512]
    __shared__ float Lt[8][64][17];         // [wave][batch][hidden-idx], padded
    int tid = threadIdx.x;
    int lane = tid & 63, wave = tid >> 6;
    int q = wave & 3, khalf = wave >> 2;
    int n0 = blockIdx.x * 64 + q * 16;
    int coln = lane & 15;
    int kq  = (lane >> 4) * 8;
    int kbase = khalf * 640;
    const _Float16* wrow  = Wcat + (size_t)(n0 + coln) * 1280 + kbase + kq;
    const _Float16* abase = xg + kbase + kq;
    floatx4 acc[4] = {};
    #pragma unroll 5
    for (int k0 = 0; k0 < 640; k0 += 32) {
        half8 fb = *(const half8*)(wrow + k0);
        #pragma unroll
        for (int mi = 0; mi < 4; ++mi) {
            half8 fa = *(const half8*)(abase + (size_t)(mi * 16 + coln) * 1280 + k0);
            acc[mi] = __builtin_amdgcn_mfma_f32_16x16x32_f16(fa, fb, acc[mi], 0, 0, 0);
        }
    }
    int rbase = (lane >> 4) * 4;
    #pragma unroll
    for (int mi = 0; mi < 4; ++mi)
        #pragma unroll
        for (int r = 0; r < 4; ++r)
            Lt[wave][mi * 16 + rbase + r][coln] = acc[mi][r];
    __syncthreads();
    int HB = blockIdx.x * 16;
    #pragma unroll
    for (int p = tid; p < 1024; p += 512) {
        int b = p >> 4, i = p & 15;
        float G0 = Lt[0][b][i] + Lt[4][b][i] + bcat[blockIdx.x * 64 + i];
        float G1 = Lt[1][b][i] + Lt[5][b][i] + bcat[blockIdx.x * 64 + 16 + i];
        float G2 = Lt[2][b][i] + Lt[6][b][i] + bcat[blockIdx.x * 64 + 32 + i];
        float G3 = Lt[3][b][i] + Lt[7][b][i] + bcat[blockIdx.x * 64 + 48 + i];
        float rr = 1.f / (1.f + __expf(-G0));
        float zz = 1.f / (1.f + __expf(-G1));
        float nn = tanhf(G2 + rr * G3);
        float h  = hprev[b * H_ + HB + i];
        float hv = (1.f - zz) * nn + zz * h;
        out[b * H_ + HB + i] = hv;               // gru_out
        out[B_ * H_ + b * H_ + HB + i] = hv;     // new_hidden
        xcat[b * 1024 + HB + i] = (_Float16)hv;
    }
}

// ------- gen_score via f16 MFMA + fused per-block softmax partials -------
__global__ __launch_bounds__(256) void proj_stats_k(
        const _Float16* __restrict__ xcat,  // (64,1024)
        const float* __restrict__ Wp,       // (V,1024) fp32
        const float* __restrict__ bp,       // (V)
        float* __restrict__ gen,            // (64,V)
        float* __restrict__ mpart, float* __restrict__ lpart) {  // (B,NP)
    __shared__ float m_lds[4][64];
    __shared__ float l_lds[4][64];
    int lane = threadIdx.x & 63;
    int wave = threadIdx.x >> 6;
    int n0 = (blockIdx.x * 4 + wave) * 16;
    int coln = lane & 15;
    int kq  = (lane >> 4) * 8;
    const float* wrow = Wp + (size_t)(n0 + coln) * 1024 + kq;
    const _Float16* abase = xcat + kq;
    floatx4 acc[4] = {};
    #pragma unroll 8
    for (int k0 = 0; k0 < 1024; k0 += 32) {
        const float4* wb = (const float4*)(wrow + k0);
        float4 w0 = wb[0], w1 = wb[1];
        half8 fb;
        fb[0] = (_Float16)w0.x; fb[1] = (_Float16)w0.y; fb[2] = (_Float16)w0.z; fb[3] = (_Float16)w0.w;
        fb[4] = (_Float16)w1.x; fb[5] = (_Float16)w1.y; fb[6] = (_Float16)w1.z; fb[7] = (_Float16)w1.w;
        #pragma unroll
        for (int mi = 0; mi < 4; ++mi) {
            half8 fa = *(const half8*)(abase + (size_t)(mi * 16 + coln) * 1024 + k0);
            acc[mi] = __builtin_amdgcn_mfma_f32_16x16x32_f16(fa, fb, acc[mi], 0, 0, 0);
        }
    }
    int rbase = (lane >> 4) * 4;
    float bias = bp[n0 + coln];
    #pragma unroll
    for (int mi = 0; mi < 4; ++mi)
        #pragma unroll
        for (int r = 0; r < 4; ++r) {
            int brow = mi * 16 + rbase + r;
            float x = acc[mi][r] + bias;
            gen[(size_t)brow * V_ + n0 + coln] = x;
            float mm = x;
            mm = fmaxf(mm, __shfl_xor(mm, 1));
            mm = fmaxf(mm, __shfl_xor(mm, 2));
            mm = fmaxf(mm, __shfl_xor(mm, 4));
            mm = fmaxf(mm, __shfl_xor(mm, 8));
            float e = __expf(x - mm);
            e += __shfl_xor(e, 1);
            e += __shfl_xor(e, 2);
            e += __shfl_xor(e, 4);
            e += __shfl_xor(e, 8);
            if (coln == 0) { m_lds[wave][brow] = mm; l_lds[wave][brow] = e; }
        }
    __syncthreads();
    if (threadIdx.x < 64) {
        int bb = threadIdx.x;
        float M = m_lds[0][bb], L = l_lds[0][bb];
        #pragma unroll
        for (int w = 1; w < 4; ++w) {
            float m2 = m_lds[w][bb], l2 = l_lds[w][bb];
            float nm = fmaxf(M, m2);
            L = L * __expf(M - nm) + l2 * __expf(m2 - nm);
            M = nm;
        }
        mpart[bb * NP_ + blockIdx.x] = M;
        lpart[bb * NP_ + blockIdx.x] = L;
    }
}

// ---- raw = cs . h_new + copy stats + scatter + FUSED params combine ----
__global__ __launch_bounds__(256) void raw_epi_k(
        const _Float16* __restrict__ cs, const float* __restrict__ hnew,
        const int* __restrict__ u_input,
        const float* __restrict__ mpart, const float* __restrict__ lpart,
        float* __restrict__ scat, float* __restrict__ params) {
    __shared__ float rawS[T_];
    __shared__ float red[T_];
    __shared__ float ms[256], ls[256];
    int b = blockIdx.x, tid = threadIdx.x;
    int lane = tid & 63, wave = tid >> 6;
    const float4* hp = (const float4*)(hnew + b * H_ + lane * 8);
    float4 ha = hp[0], hb = hp[1];
    #pragma unroll 4
    for (int i = 0; i < 32; ++i) {
        int t = wave * 32 + i;
        half8 c8 = *(const half8*)(cs + (size_t)(b * T_ + t) * H_ + lane * 8);
        float s = (float)c8[0] * ha.x + (float)c8[1] * ha.y + (float)c8[2] * ha.z + (float)c8[3] * ha.w
                + (float)c8[4] * hb.x + (float)c8[5] * hb.y + (float)c8[6] * hb.z + (float)c8[7] * hb.w;
        #pragma unroll
        for (int off = 32; off > 0; off >>= 1) s += __shfl_down(s, off);
        if (lane == 0) rawS[t] = s;
    }
    __syncthreads();
    int t = tid;
    float v = (t < T_) ? rawS[t] : -1e30f;
    if (t < T_) red[t] = v;
    __syncthreads();
    for (int s = 64; s > 0; s >>= 1) { if (t < s) red[t] = fmaxf(red[t], red[t + s]); __syncthreads(); }
    float cm = red[0]; __syncthreads();
    float e = (t < T_) ? __expf(v - cm) : 0.f;
    if (t < T_) red[t] = e;
    __syncthreads();
    for (int s = 64; s > 0; s >>= 1) { if (t < s) red[t] += red[t + s]; __syncthreads(); }
    float tot = red[0]; __syncthreads();
    int id = (t < T_) ? u_input[t * B_ + b] : 0;
    size_t j = (size_t)b * VT_ + ((id == UNK_) ? (V_ + t) : id);
    if (id != 0) scat[j] = 0.f;
    __syncthreads();
    if (id != 0) atomicAdd(&scat[j], e);
    if (t < T_) red[t] = (id != 0) ? e : 0.f;
    __syncthreads();
    for (int s = 64; s > 0; s >>= 1) { if (t < s) red[t] += red[t + s]; __syncthreads(); }
    float ssum = red[0]; __syncthreads();
    float sv = (id != 0) ? scat[j] : 0.f;
    if (t < T_) red[t] = sv;
    __syncthreads();
    for (int s = 64; s > 0; s >>= 1) { if (t < s) red[t] = fmaxf(red[t], red[t + s]); __syncthreads(); }
    float smax = red[0]; __syncthreads();
    // fused combine of gen-softmax partials (all 256 threads)
    float M = -1e30f, L = 0.f;
    for (int s = t; s < NP_; s += 256) {
        float m2 = mpart[b * NP_ + s], l2 = lpart[b * NP_ + s];
        float nm = fmaxf(M, m2);
        L = L * __expf(M - nm) + l2 * __expf(m2 - nm);
        M = nm;
    }
    ms[t] = M; ls[t] = L;
    __syncthreads();
    for (int s = 128; s > 0; s >>= 1) {
        if (t < s) {
            float m2 = ms[t + s], l2 = ls[t + s];
            float nm = fmaxf(ms[t], m2);
            ls[t] = ls[t] * __expf(ms[t] - nm) + l2 * __expf(m2 - nm);
            ms[t] = nm;
        }
        __syncthreads();
    }
    if (t == 0) {
        float Mg = ms[0], Zg = ls[0];
        float umax = cm + logf(EPS_ * tot + (1.f - EPS_) * smax);
        float M2 = fmaxf(Mg, umax);
        float coef = __expf(cm - M2);
        float Z = Zg * __expf(Mg - M2) + coef * (EPS_ * tot * (float)VT_ + (1.f - EPS_) * ssum);
        float invZ = 1.f / Z;
        params[b * 4 + 0] = M2;
        params[b * 4 + 1] = invZ;
        params[b * 4 + 2] = coef * EPS_ * tot * invZ;      // addc
        params[b * 4 + 3] = coef * (1.f - EPS_) * invZ;    // scoef
    }
}

// ---------------- streamed proba write (no scat read) ----------------
__global__ __launch_bounds__(256) void write_k(const float* __restrict__ gen,
                                               const float* __restrict__ params,
                                               float* __restrict__ proba) {
    int b = blockIdx.y;
    int i4 = blockIdx.x * 256 + threadIdx.x;   // float4 index
    if (i4 >= VT_ / 4) return;
    float M = params[b * 4], invZ = params[b * 4 + 1], addc = params[b * 4 + 2];
    int j = i4 * 4;
    float4 p;
    if (j < V_) {
        float4 g = *(const float4*)(gen + (size_t)b * V_ + j);
        p.x = addc + __expf(g.x - M) * invZ;
        p.y = addc + __expf(g.y - M) * invZ;
        p.z = addc + __expf(g.z - M) * invZ;
        p.w = addc + __expf(g.w - M) * invZ;
    } else {
        p.x = p.y = p.z = p.w = addc;
    }
    *(float4*)(proba + (size_t)b * VT_ + j) = p;
}

// ---------------- overwrite scattered positions with full value ----------
__global__ void fix_k(const float* __restrict__ gen, const float* __restrict__ scat,
                      const int* __restrict__ u_input, const float* __restrict__ params,
                      float* __restrict__ proba) {
    int b = blockIdx.x, t = threadIdx.x;
    int id = u_input[t * B_ + b];
    if (id == 0) return;
    int j = (id == UNK_) ? (V_ + t) : id;
    float M = params[b * 4], invZ = params[b * 4 + 1];
    float addc = params[b * 4 + 2], scoef = params[b * 4 + 3];
    float p = addc + scoef * scat[(size_t)b * VT_ + j];
    if (j < V_) p += __expf(gen[(size_t)b * V_ + j] - M) * invZ;
    proba[(size_t)b * VT_ + j] = p;
}

extern "C" void kernel_launch(void* const* d_in, const int* in_sizes, int n_in,
                              void* d_out, int out_size, void* d_ws, size_t ws_size,
                              hipStream_t stream) {
    const float* u_enc   = (const float*)d_in[0];
    const int*   z_tm1   = (const int*)d_in[1];
    const float* last_h  = (const float*)d_in[2];
    const int*   u_input = (const int*)d_in[3];
    const float* emb     = (const float*)d_in[4];
    const float* attn_W  = (const float*)d_in[5];
    const float* attn_b  = (const float*)d_in[6];
    const float* attn_v  = (const float*)d_in[7];
    const float* gru_Wih = (const float*)d_in[8];
    const float* gru_Whh = (const float*)d_in[9];
    const float* gru_bih = (const float*)d_in[10];
    const float* gru_bhh = (const float*)d_in[11];
    const float* proj_W  = (const float*)d_in[12];
    const float* proj_b  = (const float*)d_in[13];
    const float* copy1_W = (const float*)d_in[14];
    const float* copy1_b = (const float*)d_in[15];
    float* out = (float*)d_out;

    float* ws    = (float*)d_ws;
    float* score = ws;                          // B*T (zeroed by prologue)
    float* gen   = score + B_ * T_;             // B*V (direct store)
    float* scat  = gen + (size_t)B_ * V_;       // B*VT (sparse-zeroed)
    float* Wh    = scat + (size_t)B_ * VT_;     // B*H
    float* mpart = Wh + B_ * H_;                // B*NP
    float* lpart = mpart + B_ * NP_;            // B*NP
    float* params= lpart + B_ * NP_;            // B*4
    float* bcat  = params + B_ * 4;             // 2048
    _Float16* xcat  = (_Float16*)(bcat + 2048);        // 64*1024
    _Float16* xg    = xcat + B_ * 1024;                // 64*1280
    _Float16* Wb_attn = xg + B_ * 1280;                // 512*512
    _Float16* Wb_copy = Wb_attn + H_ * H_;             // 512*512
    _Float16* Wcat  = Wb_copy + H_ * H_;               // 2048*1280
    _Float16* cs    = Wcat + 2048 * 1280;              // 8192*512

    prologue_k<<<NB_PRO, 256, 0, stream>>>(attn_W, copy1_W, last_h, attn_b,
                                           emb, z_tm1, gru_Wih, gru_Whh, gru_bih, gru_bhh,
                                           score, Wb_attn, Wb_copy, Wh, Wcat, xg, bcat);

    enc_dual_k<<<1024, 256, 0, stream>>>(u_enc, Wb_attn, Wb_copy, Wh, attn_v, copy1_b,
                                         score, cs);

    softctx_k<<<B_, 256, 0, stream>>>(score, u_enc, xcat, xg);

    grucat_k<<<32, 512, 0, stream>>>(xg, Wcat, bcat, last_h, out, xcat);

    proj_stats_k<<<NP_, 256, 0, stream>>>(xcat, proj_W, proj_b, gen, mpart, lpart);

    raw_epi_k<<<B_, 256, 0, stream>>>(cs, out, u_input, mpart, lpart, scat, params);

    float* proba = out + 2 * B_ * H_;
    write_k<<<dim3((VT_ / 4 + 255) / 256, B_), 256, 0, stream>>>(gen, params, proba);
    fix_k<<<B_, T_, 0, stream>>>(gen, scat, u_input, params, proba);
}

// Round 6
// 355.456 us; speedup vs baseline: 1.0736x; 1.0489x over previous
//
#include <hip/hip_runtime.h>
#include <math.h>

#define T_ 128
#define B_ 64
#define H_ 512
#define E_ 256
#define V_ 32000
#define VT_ (V_ + T_)   // 32128
#define UNK_ 2
#define EPS_ 1e-10f
#define NP_ (V_ / 64)   // 500 proj blocks -> per-row softmax partials

typedef __attribute__((ext_vector_type(8))) _Float16 half8;
typedef __attribute__((ext_vector_type(2))) _Float16 half2v;
typedef __attribute__((ext_vector_type(4))) float floatx4;

// ---------------- K1: fused prologue ----------------
#define NB_ZERO 32      // 8192 floats (score)
#define NB_CVTA 512
#define NB_CVTC 512
#define NB_WH   8192    // 64*512 waves / 4
#define NB_CVTW 2048    // one block per Wcat row
#define NB_XE   64
#define NB_XH   128
#define NB_BC   8
#define NB_PRO (NB_ZERO + NB_CVTA + NB_CVTC + NB_WH + NB_CVTW + NB_XE + NB_XH + NB_BC)

// Gate-interleaved Wcat layout: permuted row mp (0..2047):
//   blk = mp>>6, q = (mp>>4)&3, idx = mp&15, hh = blk*16+idx
//   q=0 -> r-gate row hh:      [Wih_r | Whh_r]
//   q=1 -> z-gate row 512+hh:  [Wih_z | Whh_z]
//   q=2 -> n_i row 1024+hh:    [Wih_n | 0]
//   q=3 -> n_h row 1024+hh:    [0 | Whh_n]
__global__ __launch_bounds__(256) void prologue_k(
        const float* __restrict__ attn_W,
        const float* __restrict__ copy1_W, const float* __restrict__ last_h,
        const float* __restrict__ attn_b, const float* __restrict__ emb,
        const int* __restrict__ z, const float* __restrict__ Wih,
        const float* __restrict__ Whh, const float* __restrict__ bih,
        const float* __restrict__ bhh,
        float* __restrict__ zbase,
        _Float16* __restrict__ Wb_attn, _Float16* __restrict__ Wb_copy,
        float* __restrict__ Wh, _Float16* __restrict__ Wcat,
        _Float16* __restrict__ xg, float* __restrict__ bcat) {
    int bid = blockIdx.x, tid = threadIdx.x;
    if (bid < NB_ZERO) { zbase[bid * 256 + tid] = 0.f; return; }
    bid -= NB_ZERO;
    if (bid < NB_CVTA) {
        int c = tid * 2;
        float2 v = *(const float2*)(attn_W + (size_t)bid * 1024 + 512 + c);
        Wb_attn[bid * 512 + c]     = (_Float16)v.x;
        Wb_attn[bid * 512 + c + 1] = (_Float16)v.y;
        return;
    }
    bid -= NB_CVTA;
    if (bid < NB_CVTC) {
        int c = tid * 2;
        float2 v = *(const float2*)(copy1_W + (size_t)bid * 512 + c);
        Wb_copy[bid * 512 + c]     = (_Float16)v.x;
        Wb_copy[bid * 512 + c + 1] = (_Float16)v.y;
        return;
    }
    bid -= NB_CVTC;
    if (bid < NB_WH) {
        int wid = bid * 4 + (tid >> 6), lane = tid & 63;
        int b = wid >> 9, m = wid & 511;
        const float4* wr = (const float4*)(attn_W + (size_t)m * 1024);
        const float4* xr = (const float4*)(last_h + b * 512);
        float s = 0.f;
        #pragma unroll
        for (int i = 0; i < 2; ++i) {
            int k = lane + i * 64;
            float4 w = wr[k], x = xr[k];
            s += w.x * x.x + w.y * x.y + w.z * x.z + w.w * x.w;
        }
        #pragma unroll
        for (int off = 32; off > 0; off >>= 1) s += __shfl_down(s, off);
        if (lane == 0) Wh[b * 512 + m] = s + attn_b[m];
        return;
    }
    bid -= NB_WH;
    if (bid < NB_CVTW) {
        int mp = bid;
        int q  = (mp >> 4) & 3;
        int hh = (mp >> 6) * 16 + (mp & 15);
        #pragma unroll
        for (int j = 0; j < 5; ++j) {
            int c = j * 256 + tid;
            float w;
            if (q == 0)      w = (c < 768) ? Wih[(size_t)hh * 768 + c]
                                           : Whh[(size_t)hh * 512 + (c - 768)];
            else if (q == 1) w = (c < 768) ? Wih[(size_t)(512 + hh) * 768 + c]
                                           : Whh[(size_t)(512 + hh) * 512 + (c - 768)];
            else if (q == 2) w = (c < 768) ? Wih[(size_t)(1024 + hh) * 768 + c] : 0.f;
            else             w = (c >= 768) ? Whh[(size_t)(1024 + hh) * 512 + (c - 768)] : 0.f;
            Wcat[(size_t)mp * 1280 + c] = (_Float16)w;
        }
        return;
    }
    bid -= NB_CVTW;
    if (bid < NB_XE) {
        int idx = bid * 256 + tid;
        int bb = idx >> 8, c = idx & 255;
        xg[bb * 1280 + c] = (_Float16)emb[(size_t)z[bb] * E_ + c];
        return;
    }
    bid -= NB_XE;
    if (bid < NB_XH) {
        int idx = bid * 256 + tid;
        int bb = idx >> 9, c = idx & 511;
        xg[bb * 1280 + 768 + c] = (_Float16)last_h[bb * H_ + c];
        return;
    }
    bid -= NB_XH;
    {
        int mp = bid * 256 + tid;
        int q  = (mp >> 4) & 3;
        int hh = (mp >> 6) * 16 + (mp & 15);
        float v2;
        if (q == 0)      v2 = bih[hh] + bhh[hh];
        else if (q == 1) v2 = bih[512 + hh] + bhh[512 + hh];
        else if (q == 2) v2 = bih[1024 + hh];
        else             v2 = bhh[1024 + hh];
        bcat[mp] = v2;
    }
}

// ------- enc dual GEMM: 128-col blocks, 8 waves, LDS-staged A (fp32->f16),
//         XCD-remapped. A logical row (b,t) read from u_enc (T,B,H) fp32. ----
__global__ __launch_bounds__(512) void enc_dual_k(
        const float* __restrict__ u_enc,     // (T,B,H) fp32
        const _Float16* __restrict__ Wa,     // (512,512)
        const _Float16* __restrict__ Wc,     // (512,512)
        const float* __restrict__ Wh,        // (B,H) add for attn
        const float* __restrict__ attn_v,    // (H)
        const float* __restrict__ copy1_b,   // (H)
        float* __restrict__ score,           // (B*T), zeroed
        _Float16* __restrict__ cs) {         // (B*T, H)
    __shared__ _Float16 As[64 * 512];        // 64 KB, swizzled
    int bid = blockIdx.x;
    // XCD remap: xcd = bid&7 owns 16 contiguous row-tiles across all 4 col-tiles
    int xcd = bid & 7, loc = bid >> 3;       // loc 0..63
    int xt = xcd * 16 + (loc & 15);          // row-tile 0..127
    int yt = loc >> 4;                       // col-tile 0..3 (128 cols each)
    int b  = xt >> 1;                        // tile never crosses b (T=128)
    int t0 = (xt & 1) * 64;
    int r0 = b * T_ + t0;                    // global row base (b*T + t)
    int tid = threadIdx.x;
    int lane = tid & 63, wave = tid >> 6;
    // ---- stage A tile: coalesced fp32 read + cvt, swizzled LDS write ----
    const float* srcb = u_enc + (size_t)t0 * B_ * H_ + (size_t)b * H_;
    #pragma unroll
    for (int i = 0; i < 8; ++i) {
        int G = i * 512 + tid;               // 8-elem-chunk index, 0..4095
        int r = G >> 6, s = G & 63;
        const float4* p = (const float4*)(srcb + (size_t)r * B_ * H_ + s * 8);
        float4 a0 = p[0], a1 = p[1];
        half8 v;
        v[0] = (_Float16)a0.x; v[1] = (_Float16)a0.y; v[2] = (_Float16)a0.z; v[3] = (_Float16)a0.w;
        v[4] = (_Float16)a1.x; v[5] = (_Float16)a1.y; v[6] = (_Float16)a1.z; v[7] = (_Float16)a1.w;
        *(half8*)&As[(size_t)(((r << 6) | (s ^ (r & 7))) << 3)] = v;
    }
    __syncthreads();
    int n0 = yt * 128 + (wave >> 2) * 64 + (wave & 3) * 16;
    int coln = lane & 15;
    int g = lane >> 4;
    const _Float16* wra = Wa + (size_t)(n0 + coln) * H_ + g * 8;
    const _Float16* wrc = Wc + (size_t)(n0 + coln) * H_ + g * 8;
    floatx4 acca[4] = {}, accc[4] = {};
    #pragma unroll 4
    for (int k0 = 0; k0 < H_; k0 += 32) {
        half8 fba = *(const half8*)(wra + k0);
        half8 fbc = *(const half8*)(wrc + k0);
        #pragma unroll
        for (int mi = 0; mi < 4; ++mi) {
            int r = mi * 16 + coln;
            half8 fa = *(const half8*)&As[((size_t)r << 9) +
                          ((((k0 >> 3) + g) ^ (coln & 7)) << 3)];
            acca[mi] = __builtin_amdgcn_mfma_f32_16x16x32_f16(fa, fba, acca[mi], 0, 0, 0);
            accc[mi] = __builtin_amdgcn_mfma_f32_16x16x32_f16(fa, fbc, accc[mi], 0, 0, 0);
        }
    }
    int col = n0 + coln;
    float addt = Wh[b * H_ + col];
    float av   = attn_v[col];
    float cb   = copy1_b[col];
    int rbase = g * 4;
    #pragma unroll
    for (int mi = 0; mi < 4; ++mi)
        #pragma unroll
        for (int r = 0; r < 4; ++r) {
            int row = r0 + mi * 16 + rbase + r;
            float x = acca[mi][r] + addt;
            float t2 = __expf(2.f * x);
            float v = av * ((t2 - 1.f) / (t2 + 1.f));
            v += __shfl_xor(v, 1);
            v += __shfl_xor(v, 2);
            v += __shfl_xor(v, 4);
            v += __shfl_xor(v, 8);
            if (coln == 0) atomicAdd(&score[row], v);
            float y = accc[mi][r] + cb;
            float t3 = __expf(2.f * y);
            cs[(size_t)row * H_ + col] = (_Float16)((t3 - 1.f) / (t3 + 1.f));
        }
}

// ------- softmax over T + ctx: grid (B,2), 128 thr, 2 cols/thread ----
__global__ __launch_bounds__(128) void softctx_k(
        const float* __restrict__ score, const float* __restrict__ u_enc,
        _Float16* __restrict__ xcat, _Float16* __restrict__ xg) {
    __shared__ float al[T_];
    __shared__ float red[T_];
    int b = blockIdx.x, tid = threadIdx.x;   // 128 threads
    float v = score[b * T_ + tid];
    red[tid] = v;
    __syncthreads();
    for (int s = 64; s > 0; s >>= 1) { if (tid < s) red[tid] = fmaxf(red[tid], red[tid + s]); __syncthreads(); }
    float m = red[0]; __syncthreads();
    float e = __expf(v - m);
    red[tid] = e;
    __syncthreads();
    for (int s = 64; s > 0; s >>= 1) { if (tid < s) red[tid] += red[tid + s]; __syncthreads(); }
    al[tid] = e / red[0];
    __syncthreads();
    // ctx: this block covers 256 cols; thread owns 2 adjacent cols
    int col0 = blockIdx.y * 256 + tid * 2;
    const float2* ebase = (const float2*)(u_enc + (size_t)b * H_ + col0);
    float s0 = 0.f, s1 = 0.f;
    #pragma unroll 16
    for (int t = 0; t < T_; ++t) {
        float2 u = ebase[(size_t)t * (B_ * H_ / 2)];
        float a = al[t];
        s0 += a * u.x;
        s1 += a * u.y;
    }
    half2v o; o[0] = (_Float16)s0; o[1] = (_Float16)s1;
    *(half2v*)(xcat + b * 1024 + 512 + col0) = o;
    *(half2v*)(xg + b * 1280 + 256 + col0)   = o;
}

// ------- GRU gates GEMM + fused elementwise; 512 thr, K-split across waves ---
__global__ __launch_bounds__(512) void grucat_k(
        const _Float16* __restrict__ xg,    // (64,1280)
        const _Float16* __restrict__ Wcat,  // (2048,1280) permuted rows
        const float* __restrict__ bcat,     // (2048) permuted
        const float* __restrict__ hprev,    // (64,512)
        float* __restrict__ out,            // gru_out + new_hidden
        _Float16* __restrict__ xcat) {      // (64,1024), writes [:,0:512]
    __shared__ float Lt[8][64][17];         // [wave][batch][hidden-idx], padded
    int tid = threadIdx.x;
    int lane = tid & 63, wave = tid >> 6;
    int q = wave & 3, khalf = wave >> 2;
    int n0 = blockIdx.x * 64 + q * 16;
    int coln = lane & 15;
    int kq  = (lane >> 4) * 8;
    int kbase = khalf * 640;
    const _Float16* wrow  = Wcat + (size_t)(n0 + coln) * 1280 + kbase + kq;
    const _Float16* abase = xg + kbase + kq;
    floatx4 acc[4] = {};
    #pragma unroll 5
    for (int k0 = 0; k0 < 640; k0 += 32) {
        half8 fb = *(const half8*)(wrow + k0);
        #pragma unroll
        for (int mi = 0; mi < 4; ++mi) {
            half8 fa = *(const half8*)(abase + (size_t)(mi * 16 + coln) * 1280 + k0);
            acc[mi] = __builtin_amdgcn_mfma_f32_16x16x32_f16(fa, fb, acc[mi], 0, 0, 0);
        }
    }
    int rbase = (lane >> 4) * 4;
    #pragma unroll
    for (int mi = 0; mi < 4; ++mi)
        #pragma unroll
        for (int r = 0; r < 4; ++r)
            Lt[wave][mi * 16 + rbase + r][coln] = acc[mi][r];
    __syncthreads();
    int HB = blockIdx.x * 16;
    #pragma unroll
    for (int p = tid; p < 1024; p += 512) {
        int b = p >> 4, i = p & 15;
        float G0 = Lt[0][b][i] + Lt[4][b][i] + bcat[blockIdx.x * 64 + i];
        float G1 = Lt[1][b][i] + Lt[5][b][i] + bcat[blockIdx.x * 64 + 16 + i];
        float G2 = Lt[2][b][i] + Lt[6][b][i] + bcat[blockIdx.x * 64 + 32 + i];
        float G3 = Lt[3][b][i] + Lt[7][b][i] + bcat[blockIdx.x * 64 + 48 + i];
        float rr = 1.f / (1.f + __expf(-G0));
        float zz = 1.f / (1.f + __expf(-G1));
        float nn = tanhf(G2 + rr * G3);
        float h  = hprev[b * H_ + HB + i];
        float hv = (1.f - zz) * nn + zz * h;
        out[b * H_ + HB + i] = hv;               // gru_out
        out[B_ * H_ + b * H_ + HB + i] = hv;     // new_hidden
        xcat[b * 1024 + HB + i] = (_Float16)hv;
    }
}

// ------- gen_score via f16 MFMA + fused per-block softmax partials -------
__global__ __launch_bounds__(256) void proj_stats_k(
        const _Float16* __restrict__ xcat,  // (64,1024)
        const float* __restrict__ Wp,       // (V,1024) fp32
        const float* __restrict__ bp,       // (V)
        float* __restrict__ gen,            // (64,V)
        float* __restrict__ mpart, float* __restrict__ lpart) {  // (B,NP)
    __shared__ float m_lds[4][64];
    __shared__ float l_lds[4][64];
    int lane = threadIdx.x & 63;
    int wave = threadIdx.x >> 6;
    int n0 = (blockIdx.x * 4 + wave) * 16;
    int coln = lane & 15;
    int kq  = (lane >> 4) * 8;
    const float* wrow = Wp + (size_t)(n0 + coln) * 1024 + kq;
    const _Float16* abase = xcat + kq;
    floatx4 acc[4] = {};
    #pragma unroll 8
    for (int k0 = 0; k0 < 1024; k0 += 32) {
        const float4* wb = (const float4*)(wrow + k0);
        float4 w0 = wb[0], w1 = wb[1];
        half8 fb;
        fb[0] = (_Float16)w0.x; fb[1] = (_Float16)w0.y; fb[2] = (_Float16)w0.z; fb[3] = (_Float16)w0.w;
        fb[4] = (_Float16)w1.x; fb[5] = (_Float16)w1.y; fb[6] = (_Float16)w1.z; fb[7] = (_Float16)w1.w;
        #pragma unroll
        for (int mi = 0; mi < 4; ++mi) {
            half8 fa = *(const half8*)(abase + (size_t)(mi * 16 + coln) * 1024 + k0);
            acc[mi] = __builtin_amdgcn_mfma_f32_16x16x32_f16(fa, fb, acc[mi], 0, 0, 0);
        }
    }
    int rbase = (lane >> 4) * 4;
    float bias = bp[n0 + coln];
    #pragma unroll
    for (int mi = 0; mi < 4; ++mi)
        #pragma unroll
        for (int r = 0; r < 4; ++r) {
            int brow = mi * 16 + rbase + r;
            float x = acc[mi][r] + bias;
            gen[(size_t)brow * V_ + n0 + coln] = x;
            float mm = x;
            mm = fmaxf(mm, __shfl_xor(mm, 1));
            mm = fmaxf(mm, __shfl_xor(mm, 2));
            mm = fmaxf(mm, __shfl_xor(mm, 4));
            mm = fmaxf(mm, __shfl_xor(mm, 8));
            float e = __expf(x - mm);
            e += __shfl_xor(e, 1);
            e += __shfl_xor(e, 2);
            e += __shfl_xor(e, 4);
            e += __shfl_xor(e, 8);
            if (coln == 0) { m_lds[wave][brow] = mm; l_lds[wave][brow] = e; }
        }
    __syncthreads();
    if (threadIdx.x < 64) {
        int bb = threadIdx.x;
        float M = m_lds[0][bb], L = l_lds[0][bb];
        #pragma unroll
        for (int w = 1; w < 4; ++w) {
            float m2 = m_lds[w][bb], l2 = l_lds[w][bb];
            float nm = fmaxf(M, m2);
            L = L * __expf(M - nm) + l2 * __expf(m2 - nm);
            M = nm;
        }
        mpart[bb * NP_ + blockIdx.x] = M;
        lpart[bb * NP_ + blockIdx.x] = L;
    }
}

// ---- raw = cs . h_new + copy stats + scatter + FUSED params combine ----
// 512 threads: 8 waves x 16 rows for the dot phase.
__global__ __launch_bounds__(512) void raw_epi_k(
        const _Float16* __restrict__ cs, const float* __restrict__ hnew,
        const int* __restrict__ u_input,
        const float* __restrict__ mpart, const float* __restrict__ lpart,
        float* __restrict__ scat, float* __restrict__ params) {
    __shared__ float rawS[T_];
    __shared__ float red[T_];
    __shared__ float ms[512], ls[512];
    int b = blockIdx.x, tid = threadIdx.x;
    int lane = tid & 63, wave = tid >> 6;
    const float4* hp = (const float4*)(hnew + b * H_ + lane * 8);
    float4 ha = hp[0], hb = hp[1];
    #pragma unroll 4
    for (int i = 0; i < 16; ++i) {
        int t = wave * 16 + i;
        half8 c8 = *(const half8*)(cs + (size_t)(b * T_ + t) * H_ + lane * 8);
        float s = (float)c8[0] * ha.x + (float)c8[1] * ha.y + (float)c8[2] * ha.z + (float)c8[3] * ha.w
                + (float)c8[4] * hb.x + (float)c8[5] * hb.y + (float)c8[6] * hb.z + (float)c8[7] * hb.w;
        #pragma unroll
        for (int off = 32; off > 0; off >>= 1) s += __shfl_down(s, off);
        if (lane == 0) rawS[t] = s;
    }
    __syncthreads();
    int t = tid;
    float v = (t < T_) ? rawS[t] : -1e30f;
    if (t < T_) red[t] = v;
    __syncthreads();
    for (int s = 64; s > 0; s >>= 1) { if (t < s) red[t] = fmaxf(red[t], red[t + s]); __syncthreads(); }
    float cm = red[0]; __syncthreads();
    float e = (t < T_) ? __expf(v - cm) : 0.f;
    if (t < T_) red[t] = e;
    __syncthreads();
    for (int s = 64; s > 0; s >>= 1) { if (t < s) red[t] += red[t + s]; __syncthreads(); }
    float tot = red[0]; __syncthreads();
    int id = (t < T_) ? u_input[t * B_ + b] : 0;
    size_t j = (size_t)b * VT_ + ((id == UNK_) ? (V_ + t) : id);
    if (id != 0) scat[j] = 0.f;
    __syncthreads();
    if (id != 0) atomicAdd(&scat[j], e);
    if (t < T_) red[t] = (id != 0) ? e : 0.f;
    __syncthreads();
    for (int s = 64; s > 0; s >>= 1) { if (t < s) red[t] += red[t + s]; __syncthreads(); }
    float ssum = red[0]; __syncthreads();
    float sv = (id != 0) ? scat[j] : 0.f;
    if (t < T_) red[t] = sv;
    __syncthreads();
    for (int s = 64; s > 0; s >>= 1) { if (t < s) red[t] = fmaxf(red[t], red[t + s]); __syncthreads(); }
    float smax = red[0]; __syncthreads();
    // fused combine of gen-softmax partials (all 512 threads; NP_=500 -> <=1 each)
    float M = -1e30f, L = 0.f;
    if (t < NP_) { M = mpart[b * NP_ + t]; L = lpart[b * NP_ + t]; }
    ms[t] = M; ls[t] = L;
    __syncthreads();
    for (int s = 256; s > 0; s >>= 1) {
        if (t < s) {
            float m2 = ms[t + s], l2 = ls[t + s];
            float nm = fmaxf(ms[t], m2);
            ls[t] = ls[t] * __expf(ms[t] - nm) + l2 * __expf(m2 - nm);
            ms[t] = nm;
        }
        __syncthreads();
    }
    if (t == 0) {
        float Mg = ms[0], Zg = ls[0];
        float umax = cm + logf(EPS_ * tot + (1.f - EPS_) * smax);
        float M2 = fmaxf(Mg, umax);
        float coef = __expf(cm - M2);
        float Z = Zg * __expf(Mg - M2) + coef * (EPS_ * tot * (float)VT_ + (1.f - EPS_) * ssum);
        float invZ = 1.f / Z;
        params[b * 4 + 0] = M2;
        params[b * 4 + 1] = invZ;
        params[b * 4 + 2] = coef * EPS_ * tot * invZ;      // addc
        params[b * 4 + 3] = coef * (1.f - EPS_) * invZ;    // scoef
    }
}

// ---------------- streamed proba write (no scat read) ----------------
__global__ __launch_bounds__(256) void write_k(const float* __restrict__ gen,
                                               const float* __restrict__ params,
                                               float* __restrict__ proba) {
    int b = blockIdx.y;
    int i4 = blockIdx.x * 256 + threadIdx.x;   // float4 index
    if (i4 >= VT_ / 4) return;
    float M = params[b * 4], invZ = params[b * 4 + 1], addc = params[b * 4 + 2];
    int j = i4 * 4;
    float4 p;
    if (j < V_) {
        float4 g = *(const float4*)(gen + (size_t)b * V_ + j);
        p.x = addc + __expf(g.x - M) * invZ;
        p.y = addc + __expf(g.y - M) * invZ;
        p.z = addc + __expf(g.z - M) * invZ;
        p.w = addc + __expf(g.w - M) * invZ;
    } else {
        p.x = p.y = p.z = p.w = addc;
    }
    *(float4*)(proba + (size_t)b * VT_ + j) = p;
}

// ---------------- overwrite scattered positions with full value ----------
__global__ void fix_k(const float* __restrict__ gen, const float* __restrict__ scat,
                      const int* __restrict__ u_input, const float* __restrict__ params,
                      float* __restrict__ proba) {
    int b = blockIdx.x, t = threadIdx.x;
    int id = u_input[t * B_ + b];
    if (id == 0) return;
    int j = (id == UNK_) ? (V_ + t) : id;
    float M = params[b * 4], invZ = params[b * 4 + 1];
    float addc = params[b * 4 + 2], scoef = params[b * 4 + 3];
    float p = addc + scoef * scat[(size_t)b * VT_ + j];
    if (j < V_) p += __expf(gen[(size_t)b * V_ + j] - M) * invZ;
    proba[(size_t)b * VT_ + j] = p;
}

extern "C" void kernel_launch(void* const* d_in, const int* in_sizes, int n_in,
                              void* d_out, int out_size, void* d_ws, size_t ws_size,
                              hipStream_t stream) {
    const float* u_enc   = (const float*)d_in[0];
    const int*   z_tm1   = (const int*)d_in[1];
    const float* last_h  = (const float*)d_in[2];
    const int*   u_input = (const int*)d_in[3];
    const float* emb     = (const float*)d_in[4];
    const float* attn_W  = (const float*)d_in[5];
    const float* attn_b  = (const float*)d_in[6];
    const float* attn_v  = (const float*)d_in[7];
    const float* gru_Wih = (const float*)d_in[8];
    const float* gru_Whh = (const float*)d_in[9];
    const float* gru_bih = (const float*)d_in[10];
    const float* gru_bhh = (const float*)d_in[11];
    const float* proj_W  = (const float*)d_in[12];
    const float* proj_b  = (const float*)d_in[13];
    const float* copy1_W = (const float*)d_in[14];
    const float* copy1_b = (const float*)d_in[15];
    float* out = (float*)d_out;

    float* ws    = (float*)d_ws;
    float* score = ws;                          // B*T (zeroed by prologue)
    float* gen   = score + B_ * T_;             // B*V (direct store)
    float* scat  = gen + (size_t)B_ * V_;       // B*VT (sparse-zeroed)
    float* Wh    = scat + (size_t)B_ * VT_;     // B*H
    float* mpart = Wh + B_ * H_;                // B*NP
    float* lpart = mpart + B_ * NP_;            // B*NP
    float* params= lpart + B_ * NP_;            // B*4
    float* bcat  = params + B_ * 4;             // 2048
    _Float16* xcat  = (_Float16*)(bcat + 2048);        // 64*1024
    _Float16* xg    = xcat + B_ * 1024;                // 64*1280
    _Float16* Wb_attn = xg + B_ * 1280;                // 512*512
    _Float16* Wb_copy = Wb_attn + H_ * H_;             // 512*512
    _Float16* Wcat  = Wb_copy + H_ * H_;               // 2048*1280
    _Float16* cs    = Wcat + 2048 * 1280;              // 8192*512

    prologue_k<<<NB_PRO, 256, 0, stream>>>(attn_W, copy1_W, last_h, attn_b,
                                           emb, z_tm1, gru_Wih, gru_Whh, gru_bih, gru_bhh,
                                           score, Wb_attn, Wb_copy, Wh, Wcat, xg, bcat);

    enc_dual_k<<<512, 512, 0, stream>>>(u_enc, Wb_attn, Wb_copy, Wh, attn_v, copy1_b,
                                        score, cs);

    softctx_k<<<dim3(B_, 2), 128, 0, stream>>>(score, u_enc, xcat, xg);

    grucat_k<<<32, 512, 0, stream>>>(xg, Wcat, bcat, last_h, out, xcat);

    proj_stats_k<<<NP_, 256, 0, stream>>>(xcat, proj_W, proj_b, gen, mpart, lpart);

    raw_epi_k<<<B_, 512, 0, stream>>>(cs, out, u_input, mpart, lpart, scat, params);

    float* proba = out + 2 * B_ * H_;
    write_k<<<dim3((VT_ / 4 + 255) / 256, B_), 256, 0, stream>>>(gen, params, proba);
    fix_k<<<B_, T_, 0, stream>>>(gen, scat, u_input, params, proba);
}

// Round 7
// 353.486 us; speedup vs baseline: 1.0796x; 1.0056x over previous
//
#include <hip/hip_runtime.h>
#include <math.h>

#define T_ 128
#define B_ 64
#define H_ 512
#define E_ 256
#define V_ 32000
#define VT_ (V_ + T_)   // 32128
#define UNK_ 2
#define EPS_ 1e-10f
#define NP_ (V_ / 64)   // 500 proj blocks -> per-row softmax partials

typedef __attribute__((ext_vector_type(8))) _Float16 half8;
typedef __attribute__((ext_vector_type(2))) _Float16 half2v;
typedef __attribute__((ext_vector_type(4))) float floatx4;

// ---------------- K1: fused prologue ----------------
#define NB_ZERO 32      // 8192 floats (score)
#define NB_CVTA 512
#define NB_CVTC 512
#define NB_WH   8192    // 64*512 waves / 4
#define NB_CVTW 2048    // one block per Wcat row
#define NB_XE   64
#define NB_XH   128
#define NB_BC   8
#define NB_PRO (NB_ZERO + NB_CVTA + NB_CVTC + NB_WH + NB_CVTW + NB_XE + NB_XH + NB_BC)

// Gate-interleaved Wcat layout: permuted row mp (0..2047):
//   blk = mp>>6, q = (mp>>4)&3, idx = mp&15, hh = blk*16+idx
//   q=0 -> r-gate row hh:      [Wih_r | Whh_r]
//   q=1 -> z-gate row 512+hh:  [Wih_z | Whh_z]
//   q=2 -> n_i row 1024+hh:    [Wih_n | 0]
//   q=3 -> n_h row 1024+hh:    [0 | Whh_n]
__global__ __launch_bounds__(256) void prologue_k(
        const float* __restrict__ attn_W,
        const float* __restrict__ copy1_W, const float* __restrict__ last_h,
        const float* __restrict__ attn_b, const float* __restrict__ emb,
        const int* __restrict__ z, const float* __restrict__ Wih,
        const float* __restrict__ Whh, const float* __restrict__ bih,
        const float* __restrict__ bhh,
        float* __restrict__ zbase,
        _Float16* __restrict__ Wb_attn, _Float16* __restrict__ Wb_copy,
        float* __restrict__ Wh, _Float16* __restrict__ Wcat,
        _Float16* __restrict__ xg, float* __restrict__ bcat) {
    int bid = blockIdx.x, tid = threadIdx.x;
    if (bid < NB_ZERO) { zbase[bid * 256 + tid] = 0.f; return; }
    bid -= NB_ZERO;
    if (bid < NB_CVTA) {
        int c = tid * 2;
        float2 v = *(const float2*)(attn_W + (size_t)bid * 1024 + 512 + c);
        Wb_attn[bid * 512 + c]     = (_Float16)v.x;
        Wb_attn[bid * 512 + c + 1] = (_Float16)v.y;
        return;
    }
    bid -= NB_CVTA;
    if (bid < NB_CVTC) {
        int c = tid * 2;
        float2 v = *(const float2*)(copy1_W + (size_t)bid * 512 + c);
        Wb_copy[bid * 512 + c]     = (_Float16)v.x;
        Wb_copy[bid * 512 + c + 1] = (_Float16)v.y;
        return;
    }
    bid -= NB_CVTC;
    if (bid < NB_WH) {
        int wid = bid * 4 + (tid >> 6), lane = tid & 63;
        int b = wid >> 9, m = wid & 511;
        const float4* wr = (const float4*)(attn_W + (size_t)m * 1024);
        const float4* xr = (const float4*)(last_h + b * 512);
        float s = 0.f;
        #pragma unroll
        for (int i = 0; i < 2; ++i) {
            int k = lane + i * 64;
            float4 w = wr[k], x = xr[k];
            s += w.x * x.x + w.y * x.y + w.z * x.z + w.w * x.w;
        }
        #pragma unroll
        for (int off = 32; off > 0; off >>= 1) s += __shfl_down(s, off);
        if (lane == 0) Wh[b * 512 + m] = s + attn_b[m];
        return;
    }
    bid -= NB_WH;
    if (bid < NB_CVTW) {
        int mp = bid;
        int q  = (mp >> 4) & 3;
        int hh = (mp >> 6) * 16 + (mp & 15);
        #pragma unroll
        for (int j = 0; j < 5; ++j) {
            int c = j * 256 + tid;
            float w;
            if (q == 0)      w = (c < 768) ? Wih[(size_t)hh * 768 + c]
                                           : Whh[(size_t)hh * 512 + (c - 768)];
            else if (q == 1) w = (c < 768) ? Wih[(size_t)(512 + hh) * 768 + c]
                                           : Whh[(size_t)(512 + hh) * 512 + (c - 768)];
            else if (q == 2) w = (c < 768) ? Wih[(size_t)(1024 + hh) * 768 + c] : 0.f;
            else             w = (c >= 768) ? Whh[(size_t)(1024 + hh) * 512 + (c - 768)] : 0.f;
            Wcat[(size_t)mp * 1280 + c] = (_Float16)w;
        }
        return;
    }
    bid -= NB_CVTW;
    if (bid < NB_XE) {
        int idx = bid * 256 + tid;
        int bb = idx >> 8, c = idx & 255;
        xg[bb * 1280 + c] = (_Float16)emb[(size_t)z[bb] * E_ + c];
        return;
    }
    bid -= NB_XE;
    if (bid < NB_XH) {
        int idx = bid * 256 + tid;
        int bb = idx >> 9, c = idx & 511;
        xg[bb * 1280 + 768 + c] = (_Float16)last_h[bb * H_ + c];
        return;
    }
    bid -= NB_XH;
    {
        int mp = bid * 256 + tid;
        int q  = (mp >> 4) & 3;
        int hh = (mp >> 6) * 16 + (mp & 15);
        float v2;
        if (q == 0)      v2 = bih[hh] + bhh[hh];
        else if (q == 1) v2 = bih[512 + hh] + bhh[512 + hh];
        else if (q == 2) v2 = bih[1024 + hh];
        else             v2 = bhh[1024 + hh];
        bcat[mp] = v2;
    }
}

// ------- enc dual GEMM: 128-col blocks, 8 waves, LDS-staged A (fp32->f16),
//         XCD-remapped. A logical row (b,t) read from u_enc (T,B,H) fp32. ----
__global__ __launch_bounds__(512) void enc_dual_k(
        const float* __restrict__ u_enc,     // (T,B,H) fp32
        const _Float16* __restrict__ Wa,     // (512,512)
        const _Float16* __restrict__ Wc,     // (512,512)
        const float* __restrict__ Wh,        // (B,H) add for attn
        const float* __restrict__ attn_v,    // (H)
        const float* __restrict__ copy1_b,   // (H)
        float* __restrict__ score,           // (B*T), zeroed
        _Float16* __restrict__ cs) {         // (B*T, H)
    __shared__ _Float16 As[64 * 512];        // 64 KB, swizzled
    int bid = blockIdx.x;
    int xcd = bid & 7, loc = bid >> 3;       // loc 0..63
    int xt = xcd * 16 + (loc & 15);          // row-tile 0..127
    int yt = loc >> 4;                       // col-tile 0..3 (128 cols each)
    int b  = xt >> 1;                        // tile never crosses b (T=128)
    int t0 = (xt & 1) * 64;
    int r0 = b * T_ + t0;                    // global row base (b*T + t)
    int tid = threadIdx.x;
    int lane = tid & 63, wave = tid >> 6;
    const float* srcb = u_enc + (size_t)t0 * B_ * H_ + (size_t)b * H_;
    #pragma unroll
    for (int i = 0; i < 8; ++i) {
        int G = i * 512 + tid;               // 8-elem-chunk index, 0..4095
        int r = G >> 6, s = G & 63;
        const float4* p = (const float4*)(srcb + (size_t)r * B_ * H_ + s * 8);
        float4 a0 = p[0], a1 = p[1];
        half8 v;
        v[0] = (_Float16)a0.x; v[1] = (_Float16)a0.y; v[2] = (_Float16)a0.z; v[3] = (_Float16)a0.w;
        v[4] = (_Float16)a1.x; v[5] = (_Float16)a1.y; v[6] = (_Float16)a1.z; v[7] = (_Float16)a1.w;
        *(half8*)&As[(size_t)(((r << 6) | (s ^ (r & 7))) << 3)] = v;
    }
    __syncthreads();
    int n0 = yt * 128 + (wave >> 2) * 64 + (wave & 3) * 16;
    int coln = lane & 15;
    int g = lane >> 4;
    const _Float16* wra = Wa + (size_t)(n0 + coln) * H_ + g * 8;
    const _Float16* wrc = Wc + (size_t)(n0 + coln) * H_ + g * 8;
    floatx4 acca[4] = {}, accc[4] = {};
    #pragma unroll 4
    for (int k0 = 0; k0 < H_; k0 += 32) {
        half8 fba = *(const half8*)(wra + k0);
        half8 fbc = *(const half8*)(wrc + k0);
        #pragma unroll
        for (int mi = 0; mi < 4; ++mi) {
            int r = mi * 16 + coln;
            half8 fa = *(const half8*)&As[((size_t)r << 9) +
                          ((((k0 >> 3) + g) ^ (coln & 7)) << 3)];
            acca[mi] = __builtin_amdgcn_mfma_f32_16x16x32_f16(fa, fba, acca[mi], 0, 0, 0);
            accc[mi] = __builtin_amdgcn_mfma_f32_16x16x32_f16(fa, fbc, accc[mi], 0, 0, 0);
        }
    }
    int col = n0 + coln;
    float addt = Wh[b * H_ + col];
    float av   = attn_v[col];
    float cb   = copy1_b[col];
    int rbase = g * 4;
    #pragma unroll
    for (int mi = 0; mi < 4; ++mi)
        #pragma unroll
        for (int r = 0; r < 4; ++r) {
            int row = r0 + mi * 16 + rbase + r;
            float x = acca[mi][r] + addt;
            float t2 = __expf(2.f * x);
            float v = av * ((t2 - 1.f) / (t2 + 1.f));
            v += __shfl_xor(v, 1);
            v += __shfl_xor(v, 2);
            v += __shfl_xor(v, 4);
            v += __shfl_xor(v, 8);
            if (coln == 0) atomicAdd(&score[row], v);
            float y = accc[mi][r] + cb;
            float t3 = __expf(2.f * y);
            cs[(size_t)row * H_ + col] = (_Float16)((t3 - 1.f) / (t3 + 1.f));
        }
}

// ------- softmax over T + ctx: grid (B,2), 128 thr, 2 cols/thread ----
__global__ __launch_bounds__(128) void softctx_k(
        const float* __restrict__ score, const float* __restrict__ u_enc,
        _Float16* __restrict__ xcat, _Float16* __restrict__ xg) {
    __shared__ float al[T_];
    __shared__ float red[T_];
    int b = blockIdx.x, tid = threadIdx.x;   // 128 threads
    float v = score[b * T_ + tid];
    red[tid] = v;
    __syncthreads();
    for (int s = 64; s > 0; s >>= 1) { if (tid < s) red[tid] = fmaxf(red[tid], red[tid + s]); __syncthreads(); }
    float m = red[0]; __syncthreads();
    float e = __expf(v - m);
    red[tid] = e;
    __syncthreads();
    for (int s = 64; s > 0; s >>= 1) { if (tid < s) red[tid] += red[tid + s]; __syncthreads(); }
    al[tid] = e / red[0];
    __syncthreads();
    int col0 = blockIdx.y * 256 + tid * 2;
    const float2* ebase = (const float2*)(u_enc + (size_t)b * H_ + col0);
    float s0 = 0.f, s1 = 0.f;
    #pragma unroll 16
    for (int t = 0; t < T_; ++t) {
        float2 u = ebase[(size_t)t * (B_ * H_ / 2)];
        float a = al[t];
        s0 += a * u.x;
        s1 += a * u.y;
    }
    half2v o; o[0] = (_Float16)s0; o[1] = (_Float16)s1;
    *(half2v*)(xcat + b * 1024 + 512 + col0) = o;
    *(half2v*)(xg + b * 1280 + 256 + col0)   = o;
}

// ------- GRU gates GEMM + fused elementwise; 512 thr, K-split across waves ---
__global__ __launch_bounds__(512) void grucat_k(
        const _Float16* __restrict__ xg,    // (64,1280)
        const _Float16* __restrict__ Wcat,  // (2048,1280) permuted rows
        const float* __restrict__ bcat,     // (2048) permuted
        const float* __restrict__ hprev,    // (64,512)
        float* __restrict__ out,            // gru_out + new_hidden
        _Float16* __restrict__ xcat) {      // (64,1024), writes [:,0:512]
    __shared__ float Lt[8][64][17];         // [wave][batch][hidden-idx], padded
    int tid = threadIdx.x;
    int lane = tid & 63, wave = tid >> 6;
    int q = wave & 3, khalf = wave >> 2;
    int n0 = blockIdx.x * 64 + q * 16;
    int coln = lane & 15;
    int kq  = (lane >> 4) * 8;
    int kbase = khalf * 640;
    const _Float16* wrow  = Wcat + (size_t)(n0 + coln) * 1280 + kbase + kq;
    const _Float16* abase = xg + kbase + kq;
    floatx4 acc[4] = {};
    #pragma unroll 5
    for (int k0 = 0; k0 < 640; k0 += 32) {
        half8 fb = *(const half8*)(wrow + k0);
        #pragma unroll
        for (int mi = 0; mi < 4; ++mi) {
            half8 fa = *(const half8*)(abase + (size_t)(mi * 16 + coln) * 1280 + k0);
            acc[mi] = __builtin_amdgcn_mfma_f32_16x16x32_f16(fa, fb, acc[mi], 0, 0, 0);
        }
    }
    int rbase = (lane >> 4) * 4;
    #pragma unroll
    for (int mi = 0; mi < 4; ++mi)
        #pragma unroll
        for (int r = 0; r < 4; ++r)
            Lt[wave][mi * 16 + rbase + r][coln] = acc[mi][r];
    __syncthreads();
    int HB = blockIdx.x * 16;
    #pragma unroll
    for (int p = tid; p < 1024; p += 512) {
        int b = p >> 4, i = p & 15;
        float G0 = Lt[0][b][i] + Lt[4][b][i] + bcat[blockIdx.x * 64 + i];
        float G1 = Lt[1][b][i] + Lt[5][b][i] + bcat[blockIdx.x * 64 + 16 + i];
        float G2 = Lt[2][b][i] + Lt[6][b][i] + bcat[blockIdx.x * 64 + 32 + i];
        float G3 = Lt[3][b][i] + Lt[7][b][i] + bcat[blockIdx.x * 64 + 48 + i];
        float rr = 1.f / (1.f + __expf(-G0));
        float zz = 1.f / (1.f + __expf(-G1));
        float nn = tanhf(G2 + rr * G3);
        float h  = hprev[b * H_ + HB + i];
        float hv = (1.f - zz) * nn + zz * h;
        out[b * H_ + HB + i] = hv;               // gru_out
        out[B_ * H_ + b * H_ + HB + i] = hv;     // new_hidden
        xcat[b * 1024 + HB + i] = (_Float16)hv;
    }
}

// ------- MERGED: gen_score GEMM + per-block softmax partials (blocks 0..499)
//         ∥ raw = cs.h_new + copy stats + scatter (blocks 500..563) -------
__global__ __launch_bounds__(256) void proj_raw_k(
        const _Float16* __restrict__ xcat,  // (64,1024)
        const float* __restrict__ Wp,       // (V,1024) fp32
        const float* __restrict__ bp,       // (V)
        float* __restrict__ gen,            // (64,V)
        float* __restrict__ mpart, float* __restrict__ lpart,   // (B,NP)
        const _Float16* __restrict__ cs,    // (B*T,H)
        const float* __restrict__ hnew,     // (B,H)  (= out)
        const int* __restrict__ u_input,
        float* __restrict__ scat, float* __restrict__ sc4) {
    __shared__ float m_lds[4][64];
    __shared__ float l_lds[4][64];
    __shared__ float rawS[T_];
    __shared__ float red[T_];
    if (blockIdx.x < NP_) {
        // ---------------- proj part (identical math to R6) ----------------
        int lane = threadIdx.x & 63;
        int wave = threadIdx.x >> 6;
        int n0 = (blockIdx.x * 4 + wave) * 16;
        int coln = lane & 15;
        int kq  = (lane >> 4) * 8;
        const float* wrow = Wp + (size_t)(n0 + coln) * 1024 + kq;
        const _Float16* abase = xcat + kq;
        floatx4 acc[4] = {};
        #pragma unroll 8
        for (int k0 = 0; k0 < 1024; k0 += 32) {
            const float4* wb = (const float4*)(wrow + k0);
            float4 w0 = wb[0], w1 = wb[1];
            half8 fb;
            fb[0] = (_Float16)w0.x; fb[1] = (_Float16)w0.y; fb[2] = (_Float16)w0.z; fb[3] = (_Float16)w0.w;
            fb[4] = (_Float16)w1.x; fb[5] = (_Float16)w1.y; fb[6] = (_Float16)w1.z; fb[7] = (_Float16)w1.w;
            #pragma unroll
            for (int mi = 0; mi < 4; ++mi) {
                half8 fa = *(const half8*)(abase + (size_t)(mi * 16 + coln) * 1024 + k0);
                acc[mi] = __builtin_amdgcn_mfma_f32_16x16x32_f16(fa, fb, acc[mi], 0, 0, 0);
            }
        }
        int rbase = (lane >> 4) * 4;
        float bias = bp[n0 + coln];
        #pragma unroll
        for (int mi = 0; mi < 4; ++mi)
            #pragma unroll
            for (int r = 0; r < 4; ++r) {
                int brow = mi * 16 + rbase + r;
                float x = acc[mi][r] + bias;
                gen[(size_t)brow * V_ + n0 + coln] = x;
                float mm = x;
                mm = fmaxf(mm, __shfl_xor(mm, 1));
                mm = fmaxf(mm, __shfl_xor(mm, 2));
                mm = fmaxf(mm, __shfl_xor(mm, 4));
                mm = fmaxf(mm, __shfl_xor(mm, 8));
                float e = __expf(x - mm);
                e += __shfl_xor(e, 1);
                e += __shfl_xor(e, 2);
                e += __shfl_xor(e, 4);
                e += __shfl_xor(e, 8);
                if (coln == 0) { m_lds[wave][brow] = mm; l_lds[wave][brow] = e; }
            }
        __syncthreads();
        if (threadIdx.x < 64) {
            int bb = threadIdx.x;
            float M = m_lds[0][bb], L = l_lds[0][bb];
            #pragma unroll
            for (int w = 1; w < 4; ++w) {
                float m2 = m_lds[w][bb], l2 = l_lds[w][bb];
                float nm = fmaxf(M, m2);
                L = L * __expf(M - nm) + l2 * __expf(m2 - nm);
                M = nm;
            }
            mpart[bb * NP_ + blockIdx.x] = M;
            lpart[bb * NP_ + blockIdx.x] = L;
        }
        return;
    }
    // ---------------- raw part: b = blockIdx.x - NP_ ----------------
    int b = blockIdx.x - NP_;
    int tid = threadIdx.x;
    int lane = tid & 63, wave = tid >> 6;
    const float4* hp = (const float4*)(hnew + b * H_ + lane * 8);
    float4 ha = hp[0], hb = hp[1];
    #pragma unroll 4
    for (int i = 0; i < 32; ++i) {
        int t = wave * 32 + i;
        half8 c8 = *(const half8*)(cs + (size_t)(b * T_ + t) * H_ + lane * 8);
        float s = (float)c8[0] * ha.x + (float)c8[1] * ha.y + (float)c8[2] * ha.z + (float)c8[3] * ha.w
                + (float)c8[4] * hb.x + (float)c8[5] * hb.y + (float)c8[6] * hb.z + (float)c8[7] * hb.w;
        #pragma unroll
        for (int off = 32; off > 0; off >>= 1) s += __shfl_down(s, off);
        if (lane == 0) rawS[t] = s;
    }
    __syncthreads();
    int t = tid;
    float v = (t < T_) ? rawS[t] : -1e30f;
    if (t < T_) red[t] = v;
    __syncthreads();
    for (int s = 64; s > 0; s >>= 1) { if (t < s) red[t] = fmaxf(red[t], red[t + s]); __syncthreads(); }
    float cm = red[0]; __syncthreads();
    float e = (t < T_) ? __expf(v - cm) : 0.f;
    if (t < T_) red[t] = e;
    __syncthreads();
    for (int s = 64; s > 0; s >>= 1) { if (t < s) red[t] += red[t + s]; __syncthreads(); }
    float tot = red[0]; __syncthreads();
    int id = (t < T_) ? u_input[t * B_ + b] : 0;
    size_t j = (size_t)b * VT_ + ((id == UNK_) ? (V_ + t) : id);
    if (id != 0) scat[j] = 0.f;
    __syncthreads();
    if (id != 0) atomicAdd(&scat[j], e);
    if (t < T_) red[t] = (id != 0) ? e : 0.f;
    __syncthreads();
    for (int s = 64; s > 0; s >>= 1) { if (t < s) red[t] += red[t + s]; __syncthreads(); }
    float ssum = red[0]; __syncthreads();
    float sv = (id != 0) ? scat[j] : 0.f;
    if (t < T_) red[t] = sv;
    __syncthreads();
    for (int s = 64; s > 0; s >>= 1) { if (t < s) red[t] = fmaxf(red[t], red[t + s]); __syncthreads(); }
    if (t == 0) {
        sc4[b * 4 + 0] = cm;
        sc4[b * 4 + 1] = tot;
        sc4[b * 4 + 2] = ssum;
        sc4[b * 4 + 3] = red[0];   // smax
    }
}

// ------- write + inline params-combine + inline fix (phases 0/1/2) -------
__global__ __launch_bounds__(256) void write_fix_k(
        const float* __restrict__ gen,
        const float* __restrict__ mpart, const float* __restrict__ lpart,
        const float* __restrict__ sc4, const int* __restrict__ u_input,
        const float* __restrict__ scat, float* __restrict__ proba) {
    __shared__ float ms[256], ls[256];
    __shared__ float pb[4];
    int b = blockIdx.y, tid = threadIdx.x;
    // ---- phase 0: redundant per-block combine of softmax partials ----
    float M = -1e30f, L = 0.f;
    for (int s = tid; s < NP_; s += 256) {
        float m2 = mpart[b * NP_ + s], l2 = lpart[b * NP_ + s];
        float nm = fmaxf(M, m2);
        L = L * __expf(M - nm) + l2 * __expf(m2 - nm);
        M = nm;
    }
    ms[tid] = M; ls[tid] = L;
    __syncthreads();
    for (int s = 128; s > 0; s >>= 1) {
        if (tid < s) {
            float m2 = ms[tid + s], l2 = ls[tid + s];
            float nm = fmaxf(ms[tid], m2);
            ls[tid] = ls[tid] * __expf(ms[tid] - nm) + l2 * __expf(m2 - nm);
            ms[tid] = nm;
        }
        __syncthreads();
    }
    if (tid == 0) {
        float Mg = ms[0], Zg = ls[0];
        float cm = sc4[b * 4], tot = sc4[b * 4 + 1], ssum = sc4[b * 4 + 2], smax = sc4[b * 4 + 3];
        float umax = cm + logf(EPS_ * tot + (1.f - EPS_) * smax);
        float M2 = fmaxf(Mg, umax);
        float coef = __expf(cm - M2);
        float Z = Zg * __expf(Mg - M2) + coef * (EPS_ * tot * (float)VT_ + (1.f - EPS_) * ssum);
        float invZ = 1.f / Z;
        pb[0] = M2;
        pb[1] = invZ;
        pb[2] = coef * EPS_ * tot * invZ;      // addc
        pb[3] = coef * (1.f - EPS_) * invZ;    // scoef
    }
    __syncthreads();
    float M2 = pb[0], invZ = pb[1], addc = pb[2], scoef = pb[3];
    // ---- phase 1: streamed proba write ----
    int i4 = blockIdx.x * 256 + tid;   // float4 index
    if (i4 < VT_ / 4) {
        int j = i4 * 4;
        float4 p;
        if (j < V_) {
            float4 g = *(const float4*)(gen + (size_t)b * V_ + j);
            p.x = addc + __expf(g.x - M2) * invZ;
            p.y = addc + __expf(g.y - M2) * invZ;
            p.z = addc + __expf(g.z - M2) * invZ;
            p.w = addc + __expf(g.w - M2) * invZ;
        } else {
            p.x = p.y = p.z = p.w = addc;
        }
        *(float4*)(proba + (size_t)b * VT_ + j) = p;
    }
    // ---- phase 2: overwrite scattered positions landing in this block's range
    __syncthreads();
    if (tid < T_) {
        int t = tid;
        int id = u_input[t * B_ + b];
        if (id != 0) {
            int j = (id == UNK_) ? (V_ + t) : id;
            int lo = blockIdx.x * 1024;
            if (j >= lo && j < lo + 1024) {
                float p = addc + scoef * scat[(size_t)b * VT_ + j];
                if (j < V_) p += __expf(gen[(size_t)b * V_ + j] - M2) * invZ;
                proba[(size_t)b * VT_ + j] = p;
            }
        }
    }
}

extern "C" void kernel_launch(void* const* d_in, const int* in_sizes, int n_in,
                              void* d_out, int out_size, void* d_ws, size_t ws_size,
                              hipStream_t stream) {
    const float* u_enc   = (const float*)d_in[0];
    const int*   z_tm1   = (const int*)d_in[1];
    const float* last_h  = (const float*)d_in[2];
    const int*   u_input = (const int*)d_in[3];
    const float* emb     = (const float*)d_in[4];
    const float* attn_W  = (const float*)d_in[5];
    const float* attn_b  = (const float*)d_in[6];
    const float* attn_v  = (const float*)d_in[7];
    const float* gru_Wih = (const float*)d_in[8];
    const float* gru_Whh = (const float*)d_in[9];
    const float* gru_bih = (const float*)d_in[10];
    const float* gru_bhh = (const float*)d_in[11];
    const float* proj_W  = (const float*)d_in[12];
    const float* proj_b  = (const float*)d_in[13];
    const float* copy1_W = (const float*)d_in[14];
    const float* copy1_b = (const float*)d_in[15];
    float* out = (float*)d_out;

    float* ws    = (float*)d_ws;
    float* score = ws;                          // B*T (zeroed by prologue)
    float* gen   = score + B_ * T_;             // B*V (direct store)
    float* scat  = gen + (size_t)B_ * V_;       // B*VT (sparse-zeroed)
    float* Wh    = scat + (size_t)B_ * VT_;     // B*H
    float* mpart = Wh + B_ * H_;                // B*NP
    float* lpart = mpart + B_ * NP_;            // B*NP
    float* sc4   = lpart + B_ * NP_;            // B*4
    float* bcat  = sc4 + B_ * 4;                // 2048
    _Float16* xcat  = (_Float16*)(bcat + 2048);        // 64*1024
    _Float16* xg    = xcat + B_ * 1024;                // 64*1280
    _Float16* Wb_attn = xg + B_ * 1280;                // 512*512
    _Float16* Wb_copy = Wb_attn + H_ * H_;             // 512*512
    _Float16* Wcat  = Wb_copy + H_ * H_;               // 2048*1280
    _Float16* cs    = Wcat + 2048 * 1280;              // 8192*512

    prologue_k<<<NB_PRO, 256, 0, stream>>>(attn_W, copy1_W, last_h, attn_b,
                                           emb, z_tm1, gru_Wih, gru_Whh, gru_bih, gru_bhh,
                                           score, Wb_attn, Wb_copy, Wh, Wcat, xg, bcat);

    enc_dual_k<<<512, 512, 0, stream>>>(u_enc, Wb_attn, Wb_copy, Wh, attn_v, copy1_b,
                                        score, cs);

    softctx_k<<<dim3(B_, 2), 128, 0, stream>>>(score, u_enc, xcat, xg);

    grucat_k<<<32, 512, 0, stream>>>(xg, Wcat, bcat, last_h, out, xcat);

    proj_raw_k<<<NP_ + B_, 256, 0, stream>>>(xcat, proj_W, proj_b, gen, mpart, lpart,
                                             cs, out, u_input, scat, sc4);

    float* proba = out + 2 * B_ * H_;
    write_fix_k<<<dim3((VT_ / 4 + 255) / 256, B_), 256, 0, stream>>>(
        gen, mpart, lpart, sc4, u_input, scat, proba);
}

// Round 8
// 350.263 us; speedup vs baseline: 1.0895x; 1.0092x over previous
//
#include <hip/hip_runtime.h>
#include <math.h>

#define T_ 128
#define B_ 64
#define H_ 512
#define E_ 256
#define V_ 32000
#define VT_ (V_ + T_)   // 32128
#define UNK_ 2
#define EPS_ 1e-10f
#define NP_ (V_ / 64)   // 500 proj blocks -> per-row softmax partials

typedef __attribute__((ext_vector_type(8))) _Float16 half8;
typedef __attribute__((ext_vector_type(2))) _Float16 half2v;
typedef __attribute__((ext_vector_type(4))) float floatx4;

// ---------------- K1: fused prologue ----------------
#define NB_ZERO 32      // 8192 floats (score)
#define NB_CVTA 512
#define NB_CVTC 512
#define NB_WH   8192    // 64*512 waves / 4
#define NB_CVTW 2048    // one block per Wcat row
#define NB_XE   64
#define NB_XH   128
#define NB_BC   8
#define NB_PRO (NB_ZERO + NB_CVTA + NB_CVTC + NB_WH + NB_CVTW + NB_XE + NB_XH + NB_BC)

// Gate-interleaved Wcat layout: permuted row mp (0..2047):
//   blk = mp>>6, q = (mp>>4)&3, idx = mp&15, hh = blk*16+idx
//   q=0 -> r-gate row hh:      [Wih_r | Whh_r]
//   q=1 -> z-gate row 512+hh:  [Wih_z | Whh_z]
//   q=2 -> n_i row 1024+hh:    [Wih_n | 0]
//   q=3 -> n_h row 1024+hh:    [0 | Whh_n]
__global__ __launch_bounds__(256) void prologue_k(
        const float* __restrict__ attn_W,
        const float* __restrict__ copy1_W, const float* __restrict__ last_h,
        const float* __restrict__ attn_b, const float* __restrict__ emb,
        const int* __restrict__ z, const float* __restrict__ Wih,
        const float* __restrict__ Whh, const float* __restrict__ bih,
        const float* __restrict__ bhh,
        float* __restrict__ zbase,
        _Float16* __restrict__ Wb_attn, _Float16* __restrict__ Wb_copy,
        float* __restrict__ Wh, _Float16* __restrict__ Wcat,
        _Float16* __restrict__ xg, float* __restrict__ bcat) {
    int bid = blockIdx.x, tid = threadIdx.x;
    if (bid < NB_ZERO) { zbase[bid * 256 + tid] = 0.f; return; }
    bid -= NB_ZERO;
    if (bid < NB_CVTA) {
        int c = tid * 2;
        float2 v = *(const float2*)(attn_W + (size_t)bid * 1024 + 512 + c);
        Wb_attn[bid * 512 + c]     = (_Float16)v.x;
        Wb_attn[bid * 512 + c + 1] = (_Float16)v.y;
        return;
    }
    bid -= NB_CVTA;
    if (bid < NB_CVTC) {
        int c = tid * 2;
        float2 v = *(const float2*)(copy1_W + (size_t)bid * 512 + c);
        Wb_copy[bid * 512 + c]     = (_Float16)v.x;
        Wb_copy[bid * 512 + c + 1] = (_Float16)v.y;
        return;
    }
    bid -= NB_CVTC;
    if (bid < NB_WH) {
        int wid = bid * 4 + (tid >> 6), lane = tid & 63;
        int b = wid >> 9, m = wid & 511;
        const float4* wr = (const float4*)(attn_W + (size_t)m * 1024);
        const float4* xr = (const float4*)(last_h + b * 512);
        float s = 0.f;
        #pragma unroll
        for (int i = 0; i < 2; ++i) {
            int k = lane + i * 64;
            float4 w = wr[k], x = xr[k];
            s += w.x * x.x + w.y * x.y + w.z * x.z + w.w * x.w;
        }
        #pragma unroll
        for (int off = 32; off > 0; off >>= 1) s += __shfl_down(s, off);
        if (lane == 0) Wh[b * 512 + m] = s + attn_b[m];
        return;
    }
    bid -= NB_WH;
    if (bid < NB_CVTW) {
        int mp = bid;
        int q  = (mp >> 4) & 3;
        int hh = (mp >> 6) * 16 + (mp & 15);
        #pragma unroll
        for (int j = 0; j < 5; ++j) {
            int c = j * 256 + tid;
            float w;
            if (q == 0)      w = (c < 768) ? Wih[(size_t)hh * 768 + c]
                                           : Whh[(size_t)hh * 512 + (c - 768)];
            else if (q == 1) w = (c < 768) ? Wih[(size_t)(512 + hh) * 768 + c]
                                           : Whh[(size_t)(512 + hh) * 512 + (c - 768)];
            else if (q == 2) w = (c < 768) ? Wih[(size_t)(1024 + hh) * 768 + c] : 0.f;
            else             w = (c >= 768) ? Whh[(size_t)(1024 + hh) * 512 + (c - 768)] : 0.f;
            Wcat[(size_t)mp * 1280 + c] = (_Float16)w;
        }
        return;
    }
    bid -= NB_CVTW;
    if (bid < NB_XE) {
        int idx = bid * 256 + tid;
        int bb = idx >> 8, c = idx & 255;
        xg[bb * 1280 + c] = (_Float16)emb[(size_t)z[bb] * E_ + c];
        return;
    }
    bid -= NB_XE;
    if (bid < NB_XH) {
        int idx = bid * 256 + tid;
        int bb = idx >> 9, c = idx & 511;
        xg[bb * 1280 + 768 + c] = (_Float16)last_h[bb * H_ + c];
        return;
    }
    bid -= NB_XH;
    {
        int mp = bid * 256 + tid;
        int q  = (mp >> 4) & 3;
        int hh = (mp >> 6) * 16 + (mp & 15);
        float v2;
        if (q == 0)      v2 = bih[hh] + bhh[hh];
        else if (q == 1) v2 = bih[512 + hh] + bhh[512 + hh];
        else if (q == 2) v2 = bih[1024 + hh];
        else             v2 = bhh[1024 + hh];
        bcat[mp] = v2;
    }
}

// ------- enc dual GEMM: 128-col blocks, 8 waves, LDS-staged A (fp32->f16),
//         XCD-remapped. A logical row (b,t) read from u_enc (T,B,H) fp32. ----
__global__ __launch_bounds__(512) void enc_dual_k(
        const float* __restrict__ u_enc,     // (T,B,H) fp32
        const _Float16* __restrict__ Wa,     // (512,512)
        const _Float16* __restrict__ Wc,     // (512,512)
        const float* __restrict__ Wh,        // (B,H) add for attn
        const float* __restrict__ attn_v,    // (H)
        const float* __restrict__ copy1_b,   // (H)
        float* __restrict__ score,           // (B*T), zeroed
        _Float16* __restrict__ cs) {         // (B*T, H)
    __shared__ _Float16 As[64 * 512];        // 64 KB, swizzled
    int bid = blockIdx.x;
    int xcd = bid & 7, loc = bid >> 3;       // loc 0..63
    int xt = xcd * 16 + (loc & 15);          // row-tile 0..127
    int yt = loc >> 4;                       // col-tile 0..3 (128 cols each)
    int b  = xt >> 1;                        // tile never crosses b (T=128)
    int t0 = (xt & 1) * 64;
    int r0 = b * T_ + t0;                    // global row base (b*T + t)
    int tid = threadIdx.x;
    int lane = tid & 63, wave = tid >> 6;
    const float* srcb = u_enc + (size_t)t0 * B_ * H_ + (size_t)b * H_;
    #pragma unroll
    for (int i = 0; i < 8; ++i) {
        int G = i * 512 + tid;               // 8-elem-chunk index, 0..4095
        int r = G >> 6, s = G & 63;
        const float4* p = (const float4*)(srcb + (size_t)r * B_ * H_ + s * 8);
        float4 a0 = p[0], a1 = p[1];
        half8 v;
        v[0] = (_Float16)a0.x; v[1] = (_Float16)a0.y; v[2] = (_Float16)a0.z; v[3] = (_Float16)a0.w;
        v[4] = (_Float16)a1.x; v[5] = (_Float16)a1.y; v[6] = (_Float16)a1.z; v[7] = (_Float16)a1.w;
        *(half8*)&As[(size_t)(((r << 6) | (s ^ (r & 7))) << 3)] = v;
    }
    __syncthreads();
    int n0 = yt * 128 + (wave >> 2) * 64 + (wave & 3) * 16;
    int coln = lane & 15;
    int g = lane >> 4;
    const _Float16* wra = Wa + (size_t)(n0 + coln) * H_ + g * 8;
    const _Float16* wrc = Wc + (size_t)(n0 + coln) * H_ + g * 8;
    floatx4 acca[4] = {}, accc[4] = {};
    #pragma unroll 4
    for (int k0 = 0; k0 < H_; k0 += 32) {
        half8 fba = *(const half8*)(wra + k0);
        half8 fbc = *(const half8*)(wrc + k0);
        #pragma unroll
        for (int mi = 0; mi < 4; ++mi) {
            int r = mi * 16 + coln;
            half8 fa = *(const half8*)&As[((size_t)r << 9) +
                          ((((k0 >> 3) + g) ^ (coln & 7)) << 3)];
            acca[mi] = __builtin_amdgcn_mfma_f32_16x16x32_f16(fa, fba, acca[mi], 0, 0, 0);
            accc[mi] = __builtin_amdgcn_mfma_f32_16x16x32_f16(fa, fbc, accc[mi], 0, 0, 0);
        }
    }
    int col = n0 + coln;
    float addt = Wh[b * H_ + col];
    float av   = attn_v[col];
    float cb   = copy1_b[col];
    int rbase = g * 4;
    #pragma unroll
    for (int mi = 0; mi < 4; ++mi)
        #pragma unroll
        for (int r = 0; r < 4; ++r) {
            int row = r0 + mi * 16 + rbase + r;
            float x = acca[mi][r] + addt;
            float t2 = __expf(2.f * x);
            float v = av * ((t2 - 1.f) / (t2 + 1.f));
            v += __shfl_xor(v, 1);
            v += __shfl_xor(v, 2);
            v += __shfl_xor(v, 4);
            v += __shfl_xor(v, 8);
            if (coln == 0) atomicAdd(&score[row], v);
            float y = accc[mi][r] + cb;
            float t3 = __expf(2.f * y);
            cs[(size_t)row * H_ + col] = (_Float16)((t3 - 1.f) / (t3 + 1.f));
        }
}

// ------- softmax over T + ctx: grid (B,2), 128 thr, 2 cols/thread ----
__global__ __launch_bounds__(128) void softctx_k(
        const float* __restrict__ score, const float* __restrict__ u_enc,
        _Float16* __restrict__ xcat, _Float16* __restrict__ xg) {
    __shared__ float al[T_];
    __shared__ float red[T_];
    int b = blockIdx.x, tid = threadIdx.x;   // 128 threads
    float v = score[b * T_ + tid];
    red[tid] = v;
    __syncthreads();
    for (int s = 64; s > 0; s >>= 1) { if (tid < s) red[tid] = fmaxf(red[tid], red[tid + s]); __syncthreads(); }
    float m = red[0]; __syncthreads();
    float e = __expf(v - m);
    red[tid] = e;
    __syncthreads();
    for (int s = 64; s > 0; s >>= 1) { if (tid < s) red[tid] += red[tid + s]; __syncthreads(); }
    al[tid] = e / red[0];
    __syncthreads();
    int col0 = blockIdx.y * 256 + tid * 2;
    const float2* ebase = (const float2*)(u_enc + (size_t)b * H_ + col0);
    float s0 = 0.f, s1 = 0.f;
    #pragma unroll 16
    for (int t = 0; t < T_; ++t) {
        float2 u = ebase[(size_t)t * (B_ * H_ / 2)];
        float a = al[t];
        s0 += a * u.x;
        s1 += a * u.y;
    }
    half2v o; o[0] = (_Float16)s0; o[1] = (_Float16)s1;
    *(half2v*)(xcat + b * 1024 + 512 + col0) = o;
    *(half2v*)(xg + b * 1280 + 256 + col0)   = o;
}

// ------- GRU gates GEMM + fused elementwise; 512 thr, K-split across waves ---
__global__ __launch_bounds__(512) void grucat_k(
        const _Float16* __restrict__ xg,    // (64,1280)
        const _Float16* __restrict__ Wcat,  // (2048,1280) permuted rows
        const float* __restrict__ bcat,     // (2048) permuted
        const float* __restrict__ hprev,    // (64,512)
        float* __restrict__ out,            // gru_out + new_hidden
        _Float16* __restrict__ xcat) {      // (64,1024), writes [:,0:512]
    __shared__ float Lt[8][64][17];         // [wave][batch][hidden-idx], padded
    int tid = threadIdx.x;
    int lane = tid & 63, wave = tid >> 6;
    int q = wave & 3, khalf = wave >> 2;
    int n0 = blockIdx.x * 64 + q * 16;
    int coln = lane & 15;
    int kq  = (lane >> 4) * 8;
    int kbase = khalf * 640;
    const _Float16* wrow  = Wcat + (size_t)(n0 + coln) * 1280 + kbase + kq;
    const _Float16* abase = xg + kbase + kq;
    floatx4 acc[4] = {};
    #pragma unroll 5
    for (int k0 = 0; k0 < 640; k0 += 32) {
        half8 fb = *(const half8*)(wrow + k0);
        #pragma unroll
        for (int mi = 0; mi < 4; ++mi) {
            half8 fa = *(const half8*)(abase + (size_t)(mi * 16 + coln) * 1280 + k0);
            acc[mi] = __builtin_amdgcn_mfma_f32_16x16x32_f16(fa, fb, acc[mi], 0, 0, 0);
        }
    }
    int rbase = (lane >> 4) * 4;
    #pragma unroll
    for (int mi = 0; mi < 4; ++mi)
        #pragma unroll
        for (int r = 0; r < 4; ++r)
            Lt[wave][mi * 16 + rbase + r][coln] = acc[mi][r];
    __syncthreads();
    int HB = blockIdx.x * 16;
    #pragma unroll
    for (int p = tid; p < 1024; p += 512) {
        int b = p >> 4, i = p & 15;
        float G0 = Lt[0][b][i] + Lt[4][b][i] + bcat[blockIdx.x * 64 + i];
        float G1 = Lt[1][b][i] + Lt[5][b][i] + bcat[blockIdx.x * 64 + 16 + i];
        float G2 = Lt[2][b][i] + Lt[6][b][i] + bcat[blockIdx.x * 64 + 32 + i];
        float G3 = Lt[3][b][i] + Lt[7][b][i] + bcat[blockIdx.x * 64 + 48 + i];
        float rr = 1.f / (1.f + __expf(-G0));
        float zz = 1.f / (1.f + __expf(-G1));
        float nn = tanhf(G2 + rr * G3);
        float h  = hprev[b * H_ + HB + i];
        float hv = (1.f - zz) * nn + zz * h;
        out[b * H_ + HB + i] = hv;               // gru_out
        out[B_ * H_ + b * H_ + HB + i] = hv;     // new_hidden
        xcat[b * 1024 + HB + i] = (_Float16)hv;
    }
}

// ------- MERGED: gen_score GEMM (K-split, 8 waves) + softmax partials
//         (blocks 0..499) ∥ raw = cs.h_new + copy stats (blocks 500..563) ----
__global__ __launch_bounds__(512, 4) void proj_raw_k(
        const _Float16* __restrict__ xcat,  // (64,1024)
        const float* __restrict__ Wp,       // (V,1024) fp32
        const float* __restrict__ bp,       // (V)
        float* __restrict__ gen,            // (64,V)
        float* __restrict__ mpart, float* __restrict__ lpart,   // (B,NP)
        const _Float16* __restrict__ cs,    // (B*T,H)
        const float* __restrict__ hnew,     // (B,H)  (= out)
        const int* __restrict__ u_input,
        float* __restrict__ scat, float* __restrict__ sc4) {
    __shared__ float Ct[4][64][17];          // K-half combine, padded
    __shared__ float m_lds[4][64];
    __shared__ float l_lds[4][64];
    __shared__ float rawS[T_];
    __shared__ float red[T_];
    int tid = threadIdx.x;
    int lane = tid & 63, wave = tid >> 6;
    if (blockIdx.x < NP_) {
        // -------- proj: waves (q, khalf); q=col sub-tile, khalf=K half --------
        int q = wave & 3, khalf = wave >> 2;
        int n0 = (blockIdx.x * 4 + q) * 16;
        int coln = lane & 15;
        int kq  = (lane >> 4) * 8;
        int kbase = khalf * 512;
        const float* wrow = Wp + (size_t)(n0 + coln) * 1024 + kbase + kq;
        const _Float16* abase = xcat + kbase + kq;
        floatx4 acc[4] = {};
        #pragma unroll 8
        for (int k0 = 0; k0 < 512; k0 += 32) {
            const float4* wb = (const float4*)(wrow + k0);
            float4 w0 = wb[0], w1 = wb[1];
            half8 fb;
            fb[0] = (_Float16)w0.x; fb[1] = (_Float16)w0.y; fb[2] = (_Float16)w0.z; fb[3] = (_Float16)w0.w;
            fb[4] = (_Float16)w1.x; fb[5] = (_Float16)w1.y; fb[6] = (_Float16)w1.z; fb[7] = (_Float16)w1.w;
            #pragma unroll
            for (int mi = 0; mi < 4; ++mi) {
                half8 fa = *(const half8*)(abase + (size_t)(mi * 16 + coln) * 1024 + k0);
                acc[mi] = __builtin_amdgcn_mfma_f32_16x16x32_f16(fa, fb, acc[mi], 0, 0, 0);
            }
        }
        int rbase = (lane >> 4) * 4;
        if (khalf) {
            #pragma unroll
            for (int mi = 0; mi < 4; ++mi)
                #pragma unroll
                for (int r = 0; r < 4; ++r)
                    Ct[q][mi * 16 + rbase + r][coln] = acc[mi][r];
        }
        __syncthreads();
        if (!khalf) {
            float bias = bp[n0 + coln];
            #pragma unroll
            for (int mi = 0; mi < 4; ++mi)
                #pragma unroll
                for (int r = 0; r < 4; ++r) {
                    int brow = mi * 16 + rbase + r;
                    float x = acc[mi][r] + Ct[q][brow][coln] + bias;
                    gen[(size_t)brow * V_ + n0 + coln] = x;
                    float mm = x;
                    mm = fmaxf(mm, __shfl_xor(mm, 1));
                    mm = fmaxf(mm, __shfl_xor(mm, 2));
                    mm = fmaxf(mm, __shfl_xor(mm, 4));
                    mm = fmaxf(mm, __shfl_xor(mm, 8));
                    float e = __expf(x - mm);
                    e += __shfl_xor(e, 1);
                    e += __shfl_xor(e, 2);
                    e += __shfl_xor(e, 4);
                    e += __shfl_xor(e, 8);
                    if (coln == 0) { m_lds[q][brow] = mm; l_lds[q][brow] = e; }
                }
        }
        __syncthreads();
        if (tid < 64) {
            int bb = tid;
            float M = m_lds[0][bb], L = l_lds[0][bb];
            #pragma unroll
            for (int w = 1; w < 4; ++w) {
                float m2 = m_lds[w][bb], l2 = l_lds[w][bb];
                float nm = fmaxf(M, m2);
                L = L * __expf(M - nm) + l2 * __expf(m2 - nm);
                M = nm;
            }
            mpart[bb * NP_ + blockIdx.x] = M;
            lpart[bb * NP_ + blockIdx.x] = L;
        }
        return;
    }
    // ---------------- raw part: b = blockIdx.x - NP_; 8 waves x 16 rows -------
    int b = blockIdx.x - NP_;
    const float4* hp = (const float4*)(hnew + b * H_ + lane * 8);
    float4 ha = hp[0], hb = hp[1];
    #pragma unroll 4
    for (int i = 0; i < 16; ++i) {
        int t = wave * 16 + i;
        half8 c8 = *(const half8*)(cs + (size_t)(b * T_ + t) * H_ + lane * 8);
        float s = (float)c8[0] * ha.x + (float)c8[1] * ha.y + (float)c8[2] * ha.z + (float)c8[3] * ha.w
                + (float)c8[4] * hb.x + (float)c8[5] * hb.y + (float)c8[6] * hb.z + (float)c8[7] * hb.w;
        #pragma unroll
        for (int off = 32; off > 0; off >>= 1) s += __shfl_down(s, off);
        if (lane == 0) rawS[t] = s;
    }
    __syncthreads();
    int t = tid;
    float v = (t < T_) ? rawS[t] : -1e30f;
    if (t < T_) red[t] = v;
    __syncthreads();
    for (int s = 64; s > 0; s >>= 1) { if (t < s) red[t] = fmaxf(red[t], red[t + s]); __syncthreads(); }
    float cm = red[0]; __syncthreads();
    float e = (t < T_) ? __expf(v - cm) : 0.f;
    if (t < T_) red[t] = e;
    __syncthreads();
    for (int s = 64; s > 0; s >>= 1) { if (t < s) red[t] += red[t + s]; __syncthreads(); }
    float tot = red[0]; __syncthreads();
    int id = (t < T_) ? u_input[t * B_ + b] : 0;
    size_t j = (size_t)b * VT_ + ((id == UNK_) ? (V_ + (t & 127)) : id);
    if (id != 0) scat[j] = 0.f;
    __syncthreads();
    if (id != 0) atomicAdd(&scat[j], e);
    if (t < T_) red[t] = (id != 0) ? e : 0.f;
    __syncthreads();
    for (int s = 64; s > 0; s >>= 1) { if (t < s) red[t] += red[t + s]; __syncthreads(); }
    float ssum = red[0]; __syncthreads();
    float sv = (id != 0) ? scat[j] : 0.f;
    if (t < T_) red[t] = sv;
    __syncthreads();
    for (int s = 64; s > 0; s >>= 1) { if (t < s) red[t] = fmaxf(red[t], red[t + s]); __syncthreads(); }
    if (t == 0) {
        sc4[b * 4 + 0] = cm;
        sc4[b * 4 + 1] = tot;
        sc4[b * 4 + 2] = ssum;
        sc4[b * 4 + 3] = red[0];   // smax
    }
}

// ------- write + inline params-combine + inline fix (phases 0/1/2) -------
__global__ __launch_bounds__(256) void write_fix_k(
        const float* __restrict__ gen,
        const float* __restrict__ mpart, const float* __restrict__ lpart,
        const float* __restrict__ sc4, const int* __restrict__ u_input,
        const float* __restrict__ scat, float* __restrict__ proba) {
    __shared__ float ms[256], ls[256];
    __shared__ float pb[4];
    int b = blockIdx.y, tid = threadIdx.x;
    // ---- phase 0: redundant per-block combine of softmax partials ----
    float M = -1e30f, L = 0.f;
    for (int s = tid; s < NP_; s += 256) {
        float m2 = mpart[b * NP_ + s], l2 = lpart[b * NP_ + s];
        float nm = fmaxf(M, m2);
        L = L * __expf(M - nm) + l2 * __expf(m2 - nm);
        M = nm;
    }
    ms[tid] = M; ls[tid] = L;
    __syncthreads();
    for (int s = 128; s > 0; s >>= 1) {
        if (tid < s) {
            float m2 = ms[tid + s], l2 = ls[tid + s];
            float nm = fmaxf(ms[tid], m2);
            ls[tid] = ls[tid] * __expf(ms[tid] - nm) + l2 * __expf(m2 - nm);
            ms[tid] = nm;
        }
        __syncthreads();
    }
    if (tid == 0) {
        float Mg = ms[0], Zg = ls[0];
        float cm = sc4[b * 4], tot = sc4[b * 4 + 1], ssum = sc4[b * 4 + 2], smax = sc4[b * 4 + 3];
        float umax = cm + logf(EPS_ * tot + (1.f - EPS_) * smax);
        float M2 = fmaxf(Mg, umax);
        float coef = __expf(cm - M2);
        float Z = Zg * __expf(Mg - M2) + coef * (EPS_ * tot * (float)VT_ + (1.f - EPS_) * ssum);
        float invZ = 1.f / Z;
        pb[0] = M2;
        pb[1] = invZ;
        pb[2] = coef * EPS_ * tot * invZ;      // addc
        pb[3] = coef * (1.f - EPS_) * invZ;    // scoef
    }
    __syncthreads();
    float M2 = pb[0], invZ = pb[1], addc = pb[2], scoef = pb[3];
    // ---- phase 1: streamed proba write ----
    int i4 = blockIdx.x * 256 + tid;   // float4 index
    if (i4 < VT_ / 4) {
        int j = i4 * 4;
        float4 p;
        if (j < V_) {
            float4 g = *(const float4*)(gen + (size_t)b * V_ + j);
            p.x = addc + __expf(g.x - M2) * invZ;
            p.y = addc + __expf(g.y - M2) * invZ;
            p.z = addc + __expf(g.z - M2) * invZ;
            p.w = addc + __expf(g.w - M2) * invZ;
        } else {
            p.x = p.y = p.z = p.w = addc;
        }
        *(float4*)(proba + (size_t)b * VT_ + j) = p;
    }
    // ---- phase 2: overwrite scattered positions landing in this block's range
    __syncthreads();
    if (tid < T_) {
        int t = tid;
        int id = u_input[t * B_ + b];
        if (id != 0) {
            int j = (id == UNK_) ? (V_ + t) : id;
            int lo = blockIdx.x * 1024;
            if (j >= lo && j < lo + 1024) {
                float p = addc + scoef * scat[(size_t)b * VT_ + j];
                if (j < V_) p += __expf(gen[(size_t)b * V_ + j] - M2) * invZ;
                proba[(size_t)b * VT_ + j] = p;
            }
        }
    }
}

extern "C" void kernel_launch(void* const* d_in, const int* in_sizes, int n_in,
                              void* d_out, int out_size, void* d_ws, size_t ws_size,
                              hipStream_t stream) {
    const float* u_enc   = (const float*)d_in[0];
    const int*   z_tm1   = (const int*)d_in[1];
    const float* last_h  = (const float*)d_in[2];
    const int*   u_input = (const int*)d_in[3];
    const float* emb     = (const float*)d_in[4];
    const float* attn_W  = (const float*)d_in[5];
    const float* attn_b  = (const float*)d_in[6];
    const float* attn_v  = (const float*)d_in[7];
    const float* gru_Wih = (const float*)d_in[8];
    const float* gru_Whh = (const float*)d_in[9];
    const float* gru_bih = (const float*)d_in[10];
    const float* gru_bhh = (const float*)d_in[11];
    const float* proj_W  = (const float*)d_in[12];
    const float* proj_b  = (const float*)d_in[13];
    const float* copy1_W = (const float*)d_in[14];
    const float* copy1_b = (const float*)d_in[15];
    float* out = (float*)d_out;

    float* ws    = (float*)d_ws;
    float* score = ws;                          // B*T (zeroed by prologue)
    float* gen   = score + B_ * T_;             // B*V (direct store)
    float* scat  = gen + (size_t)B_ * V_;       // B*VT (sparse-zeroed)
    float* Wh    = scat + (size_t)B_ * VT_;     // B*H
    float* mpart = Wh + B_ * H_;                // B*NP
    float* lpart = mpart + B_ * NP_;            // B*NP
    float* sc4   = lpart + B_ * NP_;            // B*4
    float* bcat  = sc4 + B_ * 4;                // 2048
    _Float16* xcat  = (_Float16*)(bcat + 2048);        // 64*1024
    _Float16* xg    = xcat + B_ * 1024;                // 64*1280
    _Float16* Wb_attn = xg + B_ * 1280;                // 512*512
    _Float16* Wb_copy = Wb_attn + H_ * H_;             // 512*512
    _Float16* Wcat  = Wb_copy + H_ * H_;               // 2048*1280
    _Float16* cs    = Wcat + 2048 * 1280;              // 8192*512

    prologue_k<<<NB_PRO, 256, 0, stream>>>(attn_W, copy1_W, last_h, attn_b,
                                           emb, z_tm1, gru_Wih, gru_Whh, gru_bih, gru_bhh,
                                           score, Wb_attn, Wb_copy, Wh, Wcat, xg, bcat);

    enc_dual_k<<<512, 512, 0, stream>>>(u_enc, Wb_attn, Wb_copy, Wh, attn_v, copy1_b,
                                        score, cs);

    softctx_k<<<dim3(B_, 2), 128, 0, stream>>>(score, u_enc, xcat, xg);

    grucat_k<<<32, 512, 0, stream>>>(xg, Wcat, bcat, last_h, out, xcat);

    proj_raw_k<<<NP_ + B_, 512, 0, stream>>>(xcat, proj_W, proj_b, gen, mpart, lpart,
                                             cs, out, u_input, scat, sc4);

    float* proba = out + 2 * B_ * H_;
    write_fix_k<<<dim3((VT_ / 4 + 255) / 256, B_), 256, 0, stream>>>(
        gen, mpart, lpart, sc4, u_input, scat, proba);
}

// Round 9
// 344.996 us; speedup vs baseline: 1.1062x; 1.0153x over previous
//
#include <hip/hip_runtime.h>
#include <math.h>

#define T_ 128
#define B_ 64
#define H_ 512
#define E_ 256
#define V_ 32000
#define VT_ (V_ + T_)   // 32128
#define UNK_ 2
#define EPS_ 1e-10f
#define NP_ (V_ / 128)  // 250 proj blocks (128 cols each) -> per-row partials

typedef __attribute__((ext_vector_type(8))) _Float16 half8;
typedef __attribute__((ext_vector_type(2))) _Float16 half2v;
typedef __attribute__((ext_vector_type(4))) float floatx4;

// ---------------- K1: fused prologue ----------------
#define NB_ZERO 32      // 8192 floats (score)
#define NB_CVTA 512
#define NB_CVTC 512
#define NB_WH   8192    // 64*512 waves / 4
#define NB_CVTW 2048    // one block per Wcat row
#define NB_XE   64
#define NB_XH   128
#define NB_BC   8
#define NB_PRO (NB_ZERO + NB_CVTA + NB_CVTC + NB_WH + NB_CVTW + NB_XE + NB_XH + NB_BC)

// Gate-interleaved Wcat layout: permuted row mp (0..2047):
//   blk = mp>>6, q = (mp>>4)&3, idx = mp&15, hh = blk*16+idx
__global__ __launch_bounds__(256) void prologue_k(
        const float* __restrict__ attn_W,
        const float* __restrict__ copy1_W, const float* __restrict__ last_h,
        const float* __restrict__ attn_b, const float* __restrict__ emb,
        const int* __restrict__ z, const float* __restrict__ Wih,
        const float* __restrict__ Whh, const float* __restrict__ bih,
        const float* __restrict__ bhh,
        float* __restrict__ zbase,
        _Float16* __restrict__ Wb_attn, _Float16* __restrict__ Wb_copy,
        float* __restrict__ Wh, _Float16* __restrict__ Wcat,
        _Float16* __restrict__ xg, float* __restrict__ bcat) {
    int bid = blockIdx.x, tid = threadIdx.x;
    if (bid < NB_ZERO) { zbase[bid * 256 + tid] = 0.f; return; }
    bid -= NB_ZERO;
    if (bid < NB_CVTA) {
        int c = tid * 2;
        float2 v = *(const float2*)(attn_W + (size_t)bid * 1024 + 512 + c);
        Wb_attn[bid * 512 + c]     = (_Float16)v.x;
        Wb_attn[bid * 512 + c + 1] = (_Float16)v.y;
        return;
    }
    bid -= NB_CVTA;
    if (bid < NB_CVTC) {
        int c = tid * 2;
        float2 v = *(const float2*)(copy1_W + (size_t)bid * 512 + c);
        Wb_copy[bid * 512 + c]     = (_Float16)v.x;
        Wb_copy[bid * 512 + c + 1] = (_Float16)v.y;
        return;
    }
    bid -= NB_CVTC;
    if (bid < NB_WH) {
        int wid = bid * 4 + (tid >> 6), lane = tid & 63;
        int b = wid >> 9, m = wid & 511;
        const float4* wr = (const float4*)(attn_W + (size_t)m * 1024);
        const float4* xr = (const float4*)(last_h + b * 512);
        float s = 0.f;
        #pragma unroll
        for (int i = 0; i < 2; ++i) {
            int k = lane + i * 64;
            float4 w = wr[k], x = xr[k];
            s += w.x * x.x + w.y * x.y + w.z * x.z + w.w * x.w;
        }
        #pragma unroll
        for (int off = 32; off > 0; off >>= 1) s += __shfl_down(s, off);
        if (lane == 0) Wh[b * 512 + m] = s + attn_b[m];
        return;
    }
    bid -= NB_WH;
    if (bid < NB_CVTW) {
        int mp = bid;
        int q  = (mp >> 4) & 3;
        int hh = (mp >> 6) * 16 + (mp & 15);
        #pragma unroll
        for (int j = 0; j < 5; ++j) {
            int c = j * 256 + tid;
            float w;
            if (q == 0)      w = (c < 768) ? Wih[(size_t)hh * 768 + c]
                                           : Whh[(size_t)hh * 512 + (c - 768)];
            else if (q == 1) w = (c < 768) ? Wih[(size_t)(512 + hh) * 768 + c]
                                           : Whh[(size_t)(512 + hh) * 512 + (c - 768)];
            else if (q == 2) w = (c < 768) ? Wih[(size_t)(1024 + hh) * 768 + c] : 0.f;
            else             w = (c >= 768) ? Whh[(size_t)(1024 + hh) * 512 + (c - 768)] : 0.f;
            Wcat[(size_t)mp * 1280 + c] = (_Float16)w;
        }
        return;
    }
    bid -= NB_CVTW;
    if (bid < NB_XE) {
        int idx = bid * 256 + tid;
        int bb = idx >> 8, c = idx & 255;
        xg[bb * 1280 + c] = (_Float16)emb[(size_t)z[bb] * E_ + c];
        return;
    }
    bid -= NB_XE;
    if (bid < NB_XH) {
        int idx = bid * 256 + tid;
        int bb = idx >> 9, c = idx & 511;
        xg[bb * 1280 + 768 + c] = (_Float16)last_h[bb * H_ + c];
        return;
    }
    bid -= NB_XH;
    {
        int mp = bid * 256 + tid;
        int q  = (mp >> 4) & 3;
        int hh = (mp >> 6) * 16 + (mp & 15);
        float v2;
        if (q == 0)      v2 = bih[hh] + bhh[hh];
        else if (q == 1) v2 = bih[512 + hh] + bhh[512 + hh];
        else if (q == 2) v2 = bih[1024 + hh];
        else             v2 = bhh[1024 + hh];
        bcat[mp] = v2;
    }
}

// ------- enc dual GEMM: 128-col blocks, 8 waves, LDS-staged A (fp32->f16),
//         XCD-remapped. ----
__global__ __launch_bounds__(512) void enc_dual_k(
        const float* __restrict__ u_enc,     // (T,B,H) fp32
        const _Float16* __restrict__ Wa,     // (512,512)
        const _Float16* __restrict__ Wc,     // (512,512)
        const float* __restrict__ Wh,        // (B,H) add for attn
        const float* __restrict__ attn_v,    // (H)
        const float* __restrict__ copy1_b,   // (H)
        float* __restrict__ score,           // (B*T), zeroed
        _Float16* __restrict__ cs) {         // (B*T, H)
    __shared__ _Float16 As[64 * 512];        // 64 KB, swizzled
    int bid = blockIdx.x;
    int xcd = bid & 7, loc = bid >> 3;       // loc 0..63
    int xt = xcd * 16 + (loc & 15);          // row-tile 0..127
    int yt = loc >> 4;                       // col-tile 0..3 (128 cols each)
    int b  = xt >> 1;                        // tile never crosses b (T=128)
    int t0 = (xt & 1) * 64;
    int r0 = b * T_ + t0;                    // global row base (b*T + t)
    int tid = threadIdx.x;
    int lane = tid & 63, wave = tid >> 6;
    const float* srcb = u_enc + (size_t)t0 * B_ * H_ + (size_t)b * H_;
    #pragma unroll
    for (int i = 0; i < 8; ++i) {
        int G = i * 512 + tid;               // 8-elem-chunk index, 0..4095
        int r = G >> 6, s = G & 63;
        const float4* p = (const float4*)(srcb + (size_t)r * B_ * H_ + s * 8);
        float4 a0 = p[0], a1 = p[1];
        half8 v;
        v[0] = (_Float16)a0.x; v[1] = (_Float16)a0.y; v[2] = (_Float16)a0.z; v[3] = (_Float16)a0.w;
        v[4] = (_Float16)a1.x; v[5] = (_Float16)a1.y; v[6] = (_Float16)a1.z; v[7] = (_Float16)a1.w;
        *(half8*)&As[(size_t)(((r << 6) | (s ^ (r & 7))) << 3)] = v;
    }
    __syncthreads();
    int n0 = yt * 128 + (wave >> 2) * 64 + (wave & 3) * 16;
    int coln = lane & 15;
    int g = lane >> 4;
    const _Float16* wra = Wa + (size_t)(n0 + coln) * H_ + g * 8;
    const _Float16* wrc = Wc + (size_t)(n0 + coln) * H_ + g * 8;
    floatx4 acca[4] = {}, accc[4] = {};
    #pragma unroll 4
    for (int k0 = 0; k0 < H_; k0 += 32) {
        half8 fba = *(const half8*)(wra + k0);
        half8 fbc = *(const half8*)(wrc + k0);
        #pragma unroll
        for (int mi = 0; mi < 4; ++mi) {
            int r = mi * 16 + coln;
            half8 fa = *(const half8*)&As[((size_t)r << 9) +
                          ((((k0 >> 3) + g) ^ (coln & 7)) << 3)];
            acca[mi] = __builtin_amdgcn_mfma_f32_16x16x32_f16(fa, fba, acca[mi], 0, 0, 0);
            accc[mi] = __builtin_amdgcn_mfma_f32_16x16x32_f16(fa, fbc, accc[mi], 0, 0, 0);
        }
    }
    int col = n0 + coln;
    float addt = Wh[b * H_ + col];
    float av   = attn_v[col];
    float cb   = copy1_b[col];
    int rbase = g * 4;
    #pragma unroll
    for (int mi = 0; mi < 4; ++mi)
        #pragma unroll
        for (int r = 0; r < 4; ++r) {
            int row = r0 + mi * 16 + rbase + r;
            float x = acca[mi][r] + addt;
            float t2 = __expf(2.f * x);
            float v = av * ((t2 - 1.f) / (t2 + 1.f));
            v += __shfl_xor(v, 1);
            v += __shfl_xor(v, 2);
            v += __shfl_xor(v, 4);
            v += __shfl_xor(v, 8);
            if (coln == 0) atomicAdd(&score[row], v);
            float y = accc[mi][r] + cb;
            float t3 = __expf(2.f * y);
            cs[(size_t)row * H_ + col] = (_Float16)((t3 - 1.f) / (t3 + 1.f));
        }
}

// ------- softmax over T + ctx: grid (B,2), 128 thr, 2 cols/thread ----
__global__ __launch_bounds__(128) void softctx_k(
        const float* __restrict__ score, const float* __restrict__ u_enc,
        _Float16* __restrict__ xcat, _Float16* __restrict__ xg) {
    __shared__ float al[T_];
    __shared__ float red[T_];
    int b = blockIdx.x, tid = threadIdx.x;   // 128 threads
    float v = score[b * T_ + tid];
    red[tid] = v;
    __syncthreads();
    for (int s = 64; s > 0; s >>= 1) { if (tid < s) red[tid] = fmaxf(red[tid], red[tid + s]); __syncthreads(); }
    float m = red[0]; __syncthreads();
    float e = __expf(v - m);
    red[tid] = e;
    __syncthreads();
    for (int s = 64; s > 0; s >>= 1) { if (tid < s) red[tid] += red[tid + s]; __syncthreads(); }
    al[tid] = e / red[0];
    __syncthreads();
    int col0 = blockIdx.y * 256 + tid * 2;
    const float2* ebase = (const float2*)(u_enc + (size_t)b * H_ + col0);
    float s0 = 0.f, s1 = 0.f;
    #pragma unroll 16
    for (int t = 0; t < T_; ++t) {
        float2 u = ebase[(size_t)t * (B_ * H_ / 2)];
        float a = al[t];
        s0 += a * u.x;
        s1 += a * u.y;
    }
    half2v o; o[0] = (_Float16)s0; o[1] = (_Float16)s1;
    *(half2v*)(xcat + b * 1024 + 512 + col0) = o;
    *(half2v*)(xg + b * 1280 + 256 + col0)   = o;
}

// ------- GRU gates GEMM + fused elementwise; 512 thr, K-split across waves ---
__global__ __launch_bounds__(512) void grucat_k(
        const _Float16* __restrict__ xg,    // (64,1280)
        const _Float16* __restrict__ Wcat,  // (2048,1280) permuted rows
        const float* __restrict__ bcat,     // (2048) permuted
        const float* __restrict__ hprev,    // (64,512)
        float* __restrict__ out,            // gru_out + new_hidden
        _Float16* __restrict__ xcat) {      // (64,1024), writes [:,0:512]
    __shared__ float Lt[8][64][17];         // [wave][batch][hidden-idx], padded
    int tid = threadIdx.x;
    int lane = tid & 63, wave = tid >> 6;
    int q = wave & 3, khalf = wave >> 2;
    int n0 = blockIdx.x * 64 + q * 16;
    int coln = lane & 15;
    int kq  = (lane >> 4) * 8;
    int kbase = khalf * 640;
    const _Float16* wrow  = Wcat + (size_t)(n0 + coln) * 1280 + kbase + kq;
    const _Float16* abase = xg + kbase + kq;
    floatx4 acc[4] = {};
    #pragma unroll 5
    for (int k0 = 0; k0 < 640; k0 += 32) {
        half8 fb = *(const half8*)(wrow + k0);
        #pragma unroll
        for (int mi = 0; mi < 4; ++mi) {
            half8 fa = *(const half8*)(abase + (size_t)(mi * 16 + coln) * 1280 + k0);
            acc[mi] = __builtin_amdgcn_mfma_f32_16x16x32_f16(fa, fb, acc[mi], 0, 0, 0);
        }
    }
    int rbase = (lane >> 4) * 4;
    #pragma unroll
    for (int mi = 0; mi < 4; ++mi)
        #pragma unroll
        for (int r = 0; r < 4; ++r)
            Lt[wave][mi * 16 + rbase + r][coln] = acc[mi][r];
    __syncthreads();
    int HB = blockIdx.x * 16;
    #pragma unroll
    for (int p = tid; p < 1024; p += 512) {
        int b = p >> 4, i = p & 15;
        float G0 = Lt[0][b][i] + Lt[4][b][i] + bcat[blockIdx.x * 64 + i];
        float G1 = Lt[1][b][i] + Lt[5][b][i] + bcat[blockIdx.x * 64 + 16 + i];
        float G2 = Lt[2][b][i] + Lt[6][b][i] + bcat[blockIdx.x * 64 + 32 + i];
        float G3 = Lt[3][b][i] + Lt[7][b][i] + bcat[blockIdx.x * 64 + 48 + i];
        float rr = 1.f / (1.f + __expf(-G0));
        float zz = 1.f / (1.f + __expf(-G1));
        float nn = tanhf(G2 + rr * G3);
        float h  = hprev[b * H_ + HB + i];
        float hv = (1.f - zz) * nn + zz * h;
        out[b * H_ + HB + i] = hv;               // gru_out
        out[B_ * H_ + b * H_ + HB + i] = hv;     // new_hidden
        xcat[b * 1024 + HB + i] = (_Float16)hv;
    }
}

// ------- MERGED: gen_score GEMM (reg-prefetched W stream, 8 col-waves,
//         blocks 0..249) ∥ raw = cs.h_new + copy stats (blocks 250..313) ----
__global__ __launch_bounds__(512, 2) void proj_raw_k(
        const _Float16* __restrict__ xcat,  // (64,1024)
        const float* __restrict__ Wp,       // (V,1024) fp32
        const float* __restrict__ bp,       // (V)
        float* __restrict__ gen,            // (64,V)
        float* __restrict__ mpart, float* __restrict__ lpart,   // (B,NP)
        const _Float16* __restrict__ cs,    // (B*T,H)
        const float* __restrict__ hnew,     // (B,H)  (= out)
        const int* __restrict__ u_input,
        float* __restrict__ scat, float* __restrict__ sc4) {
    __shared__ float m_lds[8][64];
    __shared__ float l_lds[8][64];
    __shared__ float rawS[T_];
    __shared__ float red[T_];
    int tid = threadIdx.x;
    int lane = tid & 63, wave = tid >> 6;
    if (blockIdx.x < NP_) {
        // ---- proj: wave = col sub-tile (0..7), full K; W double-buffered in regs
        int n0 = blockIdx.x * 128 + wave * 16;
        int coln = lane & 15;
        int g = lane >> 4;                   // 0..3
        const float4* wrow4 = (const float4*)(Wp + (size_t)(n0 + coln) * 1024 + g * 8);
        const _Float16* abase = xcat + g * 8;
        floatx4 acc[4] = {};
        float4 pw[2][8][2];
        #pragma unroll
        for (int i = 0; i < 8; ++i) {
            pw[0][i][0] = wrow4[i * 8];
            pw[0][i][1] = wrow4[i * 8 + 1];
        }
        #pragma unroll
        for (int c = 0; c < 4; ++c) {
            const int cur = c & 1;
            if (c < 3) {
                #pragma unroll
                for (int i = 0; i < 8; ++i) {
                    pw[cur ^ 1][i][0] = wrow4[(c + 1) * 64 + i * 8];
                    pw[cur ^ 1][i][1] = wrow4[(c + 1) * 64 + i * 8 + 1];
                }
            }
            #pragma unroll
            for (int i = 0; i < 8; ++i) {
                float4 w0 = pw[cur][i][0], w1 = pw[cur][i][1];
                half8 fb;
                fb[0] = (_Float16)w0.x; fb[1] = (_Float16)w0.y; fb[2] = (_Float16)w0.z; fb[3] = (_Float16)w0.w;
                fb[4] = (_Float16)w1.x; fb[5] = (_Float16)w1.y; fb[6] = (_Float16)w1.z; fb[7] = (_Float16)w1.w;
                int k0 = c * 256 + i * 32;
                #pragma unroll
                for (int mi = 0; mi < 4; ++mi) {
                    half8 fa = *(const half8*)(abase + (size_t)(mi * 16 + coln) * 1024 + k0);
                    acc[mi] = __builtin_amdgcn_mfma_f32_16x16x32_f16(fa, fb, acc[mi], 0, 0, 0);
                }
            }
        }
        int rbase = g * 4;
        float bias = bp[n0 + coln];
        #pragma unroll
        for (int mi = 0; mi < 4; ++mi)
            #pragma unroll
            for (int r = 0; r < 4; ++r) {
                int brow = mi * 16 + rbase + r;
                float x = acc[mi][r] + bias;
                gen[(size_t)brow * V_ + n0 + coln] = x;
                float mm = x;
                mm = fmaxf(mm, __shfl_xor(mm, 1));
                mm = fmaxf(mm, __shfl_xor(mm, 2));
                mm = fmaxf(mm, __shfl_xor(mm, 4));
                mm = fmaxf(mm, __shfl_xor(mm, 8));
                float e = __expf(x - mm);
                e += __shfl_xor(e, 1);
                e += __shfl_xor(e, 2);
                e += __shfl_xor(e, 4);
                e += __shfl_xor(e, 8);
                if (coln == 0) { m_lds[wave][brow] = mm; l_lds[wave][brow] = e; }
            }
        __syncthreads();
        if (tid < 64) {
            int bb = tid;
            float M = m_lds[0][bb], L = l_lds[0][bb];
            #pragma unroll
            for (int w = 1; w < 8; ++w) {
                float m2 = m_lds[w][bb], l2 = l_lds[w][bb];
                float nm = fmaxf(M, m2);
                L = L * __expf(M - nm) + l2 * __expf(m2 - nm);
                M = nm;
            }
            mpart[bb * NP_ + blockIdx.x] = M;
            lpart[bb * NP_ + blockIdx.x] = L;
        }
        return;
    }
    // ---------------- raw part: b = blockIdx.x - NP_; 8 waves x 16 rows -------
    int b = blockIdx.x - NP_;
    const float4* hp = (const float4*)(hnew + b * H_ + lane * 8);
    float4 ha = hp[0], hb = hp[1];
    #pragma unroll 4
    for (int i = 0; i < 16; ++i) {
        int t = wave * 16 + i;
        half8 c8 = *(const half8*)(cs + (size_t)(b * T_ + t) * H_ + lane * 8);
        float s = (float)c8[0] * ha.x + (float)c8[1] * ha.y + (float)c8[2] * ha.z + (float)c8[3] * ha.w
                + (float)c8[4] * hb.x + (float)c8[5] * hb.y + (float)c8[6] * hb.z + (float)c8[7] * hb.w;
        #pragma unroll
        for (int off = 32; off > 0; off >>= 1) s += __shfl_down(s, off);
        if (lane == 0) rawS[t] = s;
    }
    __syncthreads();
    int t = tid;
    float v = (t < T_) ? rawS[t] : -1e30f;
    if (t < T_) red[t] = v;
    __syncthreads();
    for (int s = 64; s > 0; s >>= 1) { if (t < s) red[t] = fmaxf(red[t], red[t + s]); __syncthreads(); }
    float cm = red[0]; __syncthreads();
    float e = (t < T_) ? __expf(v - cm) : 0.f;
    if (t < T_) red[t] = e;
    __syncthreads();
    for (int s = 64; s > 0; s >>= 1) { if (t < s) red[t] += red[t + s]; __syncthreads(); }
    float tot = red[0]; __syncthreads();
    int id = (t < T_) ? u_input[t * B_ + b] : 0;
    size_t j = (size_t)b * VT_ + ((id == UNK_) ? (V_ + t) : id);
    if (id != 0) scat[j] = 0.f;
    __syncthreads();
    if (id != 0) atomicAdd(&scat[j], e);
    if (t < T_) red[t] = (id != 0) ? e : 0.f;
    __syncthreads();
    for (int s = 64; s > 0; s >>= 1) { if (t < s) red[t] += red[t + s]; __syncthreads(); }
    float ssum = red[0]; __syncthreads();
    float sv = (id != 0) ? scat[j] : 0.f;
    if (t < T_) red[t] = sv;
    __syncthreads();
    for (int s = 64; s > 0; s >>= 1) { if (t < s) red[t] = fmaxf(red[t], red[t + s]); __syncthreads(); }
    if (t == 0) {
        sc4[b * 4 + 0] = cm;
        sc4[b * 4 + 1] = tot;
        sc4[b * 4 + 2] = ssum;
        sc4[b * 4 + 3] = red[0];   // smax
    }
}

// ------- write + inline params-combine + inline fix (phases 0/1/2) -------
__global__ __launch_bounds__(256) void write_fix_k(
        const float* __restrict__ gen,
        const float* __restrict__ mpart, const float* __restrict__ lpart,
        const float* __restrict__ sc4, const int* __restrict__ u_input,
        const float* __restrict__ scat, float* __restrict__ proba) {
    __shared__ float ms[256], ls[256];
    __shared__ float pb[4];
    int b = blockIdx.y, tid = threadIdx.x;
    // ---- phase 0: redundant per-block combine of softmax partials ----
    float M = -1e30f, L = 0.f;
    for (int s = tid; s < NP_; s += 256) {
        float m2 = mpart[b * NP_ + s], l2 = lpart[b * NP_ + s];
        float nm = fmaxf(M, m2);
        L = L * __expf(M - nm) + l2 * __expf(m2 - nm);
        M = nm;
    }
    ms[tid] = M; ls[tid] = L;
    __syncthreads();
    for (int s = 128; s > 0; s >>= 1) {
        if (tid < s) {
            float m2 = ms[tid + s], l2 = ls[tid + s];
            float nm = fmaxf(ms[tid], m2);
            ls[tid] = ls[tid] * __expf(ms[tid] - nm) + l2 * __expf(m2 - nm);
            ms[tid] = nm;
        }
        __syncthreads();
    }
    if (tid == 0) {
        float Mg = ms[0], Zg = ls[0];
        float cm = sc4[b * 4], tot = sc4[b * 4 + 1], ssum = sc4[b * 4 + 2], smax = sc4[b * 4 + 3];
        float umax = cm + logf(EPS_ * tot + (1.f - EPS_) * smax);
        float M2 = fmaxf(Mg, umax);
        float coef = __expf(cm - M2);
        float Z = Zg * __expf(Mg - M2) + coef * (EPS_ * tot * (float)VT_ + (1.f - EPS_) * ssum);
        float invZ = 1.f / Z;
        pb[0] = M2;
        pb[1] = invZ;
        pb[2] = coef * EPS_ * tot * invZ;      // addc
        pb[3] = coef * (1.f - EPS_) * invZ;    // scoef
    }
    __syncthreads();
    float M2 = pb[0], invZ = pb[1], addc = pb[2], scoef = pb[3];
    // ---- phase 1: streamed proba write ----
    int i4 = blockIdx.x * 256 + tid;   // float4 index
    if (i4 < VT_ / 4) {
        int j = i4 * 4;
        float4 p;
        if (j < V_) {
            float4 g = *(const float4*)(gen + (size_t)b * V_ + j);
            p.x = addc + __expf(g.x - M2) * invZ;
            p.y = addc + __expf(g.y - M2) * invZ;
            p.z = addc + __expf(g.z - M2) * invZ;
            p.w = addc + __expf(g.w - M2) * invZ;
        } else {
            p.x = p.y = p.z = p.w = addc;
        }
        *(float4*)(proba + (size_t)b * VT_ + j) = p;
    }
    // ---- phase 2: overwrite scattered positions landing in this block's range
    __syncthreads();
    if (tid < T_) {
        int t = tid;
        int id = u_input[t * B_ + b];
        if (id != 0) {
            int j = (id == UNK_) ? (V_ + t) : id;
            int lo = blockIdx.x * 1024;
            if (j >= lo && j < lo + 1024) {
                float p = addc + scoef * scat[(size_t)b * VT_ + j];
                if (j < V_) p += __expf(gen[(size_t)b * V_ + j] - M2) * invZ;
                proba[(size_t)b * VT_ + j] = p;
            }
        }
    }
}

extern "C" void kernel_launch(void* const* d_in, const int* in_sizes, int n_in,
                              void* d_out, int out_size, void* d_ws, size_t ws_size,
                              hipStream_t stream) {
    const float* u_enc   = (const float*)d_in[0];
    const int*   z_tm1   = (const int*)d_in[1];
    const float* last_h  = (const float*)d_in[2];
    const int*   u_input = (const int*)d_in[3];
    const float* emb     = (const float*)d_in[4];
    const float* attn_W  = (const float*)d_in[5];
    const float* attn_b  = (const float*)d_in[6];
    const float* attn_v  = (const float*)d_in[7];
    const float* gru_Wih = (const float*)d_in[8];
    const float* gru_Whh = (const float*)d_in[9];
    const float* gru_bih = (const float*)d_in[10];
    const float* gru_bhh = (const float*)d_in[11];
    const float* proj_W  = (const float*)d_in[12];
    const float* proj_b  = (const float*)d_in[13];
    const float* copy1_W = (const float*)d_in[14];
    const float* copy1_b = (const float*)d_in[15];
    float* out = (float*)d_out;

    float* ws    = (float*)d_ws;
    float* score = ws;                          // B*T (zeroed by prologue)
    float* gen   = score + B_ * T_;             // B*V (direct store)
    float* scat  = gen + (size_t)B_ * V_;       // B*VT (sparse-zeroed)
    float* Wh    = scat + (size_t)B_ * VT_;     // B*H
    float* mpart = Wh + B_ * H_;                // B*NP
    float* lpart = mpart + B_ * NP_;            // B*NP
    float* sc4   = lpart + B_ * NP_;            // B*4
    float* bcat  = sc4 + B_ * 4;                // 2048
    _Float16* xcat  = (_Float16*)(bcat + 2048);        // 64*1024
    _Float16* xg    = xcat + B_ * 1024;                // 64*1280
    _Float16* Wb_attn = xg + B_ * 1280;                // 512*512
    _Float16* Wb_copy = Wb_attn + H_ * H_;             // 512*512
    _Float16* Wcat  = Wb_copy + H_ * H_;               // 2048*1280
    _Float16* cs    = Wcat + 2048 * 1280;              // 8192*512

    prologue_k<<<NB_PRO, 256, 0, stream>>>(attn_W, copy1_W, last_h, attn_b,
                                           emb, z_tm1, gru_Wih, gru_Whh, gru_bih, gru_bhh,
                                           score, Wb_attn, Wb_copy, Wh, Wcat, xg, bcat);

    enc_dual_k<<<512, 512, 0, stream>>>(u_enc, Wb_attn, Wb_copy, Wh, attn_v, copy1_b,
                                        score, cs);

    softctx_k<<<dim3(B_, 2), 128, 0, stream>>>(score, u_enc, xcat, xg);

    grucat_k<<<32, 512, 0, stream>>>(xg, Wcat, bcat, last_h, out, xcat);

    proj_raw_k<<<NP_ + B_, 512, 0, stream>>>(xcat, proj_W, proj_b, gen, mpart, lpart,
                                             cs, out, u_input, scat, sc4);

    float* proba = out + 2 * B_ * H_;
    write_fix_k<<<dim3((VT_ / 4 + 255) / 256, B_), 256, 0, stream>>>(
        gen, mpart, lpart, sc4, u_input, scat, proba);
}